// Round 2
// baseline (486.075 us; speedup 1.0000x reference)
//
#include <hip/hip_runtime.h>
#include <hip/hip_bf16.h>
#include <float.h>
#include <math.h>

#define NN   50000
#define BB   50
#define NPGc 1000
#define EE   300000
#define HH   256
#define FIN  79
#define KK   500

typedef __hip_bfloat16 bf16;

__device__ __forceinline__ float b2f(bf16 v) { return __bfloat162float(v); }

// Runtime-dtype float load: flag!=0 -> buffer is fp32, else packed bf16.
__device__ __forceinline__ float ldf(const void* p, int i, bool f32) {
    return f32 ? ((const float*)p)[i] : __bfloat162float(((const bf16*)p)[i]);
}

// ---------------- dtype detection ----------------
// Reads first 10112 uint32 words of W1 (40448 B -- safe whether W1 is
// 20224 bf16 (40448 B) or 20224 fp32 (80896 B)). If bf16-packed, the low
// 16 bits of each word are a real weight |v|<1 -> bf16 exponent < 128.
// If fp32, low 16 bits are mantissa bits -> "exponent" >= 128 about half
// the time. Count and threshold.
__global__ void k_detect(const unsigned int* __restrict__ w1, int* __restrict__ flag) {
    __shared__ int sm[256];
    int t = threadIdx.x;
    int c = 0;
    for (int i = t; i < 10112; i += 256) {
        unsigned int e = (w1[i] >> 7) & 0xFFu;   // bf16 exponent of low half
        c += (e >= 128u) ? 1 : 0;
    }
    sm[t] = c;
    __syncthreads();
    for (int off = 128; off > 0; off >>= 1) {
        if (t < off) sm[t] += sm[t + off];
        __syncthreads();
    }
    if (t == 0) flag[0] = (sm[0] > 500) ? 1 : 0;
}

// ---------------- degree / CSR construction ----------------

__global__ void k_init(int* __restrict__ deg, int* __restrict__ cursor) {
    int i = blockIdx.x * blockDim.x + threadIdx.x;
    if (i < NN) { deg[i] = 0; cursor[i] = 0; }
}

__global__ void k_count(const int* __restrict__ edst, int* __restrict__ deg) {
    int e = blockIdx.x * blockDim.x + threadIdx.x;
    if (e < EE) atomicAdd(&deg[edst[e]], 1);
}

__global__ void k_scan_block(const int* __restrict__ deg, int* __restrict__ partial,
                             int* __restrict__ bsums) {
    __shared__ int sm[256];
    int t = threadIdx.x;
    int i = blockIdx.x * 256 + t;
    int v = (i < NN) ? deg[i] : 0;
    sm[t] = v;
    __syncthreads();
    for (int off = 1; off < 256; off <<= 1) {
        int u = (t >= off) ? sm[t - off] : 0;
        __syncthreads();
        sm[t] += u;
        __syncthreads();
    }
    if (i < NN) partial[i] = sm[t];
    if (t == 255) bsums[blockIdx.x] = sm[255];
}

__global__ void k_scan_sums(int* __restrict__ bsums, int nb) {
    __shared__ int sm[256];
    int t = threadIdx.x;
    int v = (t < nb) ? bsums[t] : 0;
    sm[t] = v;
    __syncthreads();
    for (int off = 1; off < 256; off <<= 1) {
        int u = (t >= off) ? sm[t - off] : 0;
        __syncthreads();
        sm[t] += u;
        __syncthreads();
    }
    if (t < nb) bsums[t] = sm[t];
}

__global__ void k_finalize(const int* __restrict__ deg, const int* __restrict__ partial,
                           const int* __restrict__ bsums, int* __restrict__ offsets,
                           float* __restrict__ dinv) {
    int b = blockIdx.x;
    int i = b * 256 + threadIdx.x;
    if (i >= NN) return;
    int incl = partial[i] + (b ? bsums[b - 1] : 0);
    offsets[i] = incl - deg[i];
    if (i == NN - 1) offsets[NN] = incl;
    dinv[i] = rsqrtf((float)(deg[i] + 1));   // +1 self-loop
}

__global__ void k_fill(const int* __restrict__ esrc, const int* __restrict__ edst,
                       const int* __restrict__ offsets, int* __restrict__ cursor,
                       int* __restrict__ eidx) {
    int e = blockIdx.x * blockDim.x + threadIdx.x;
    if (e < EE) {
        int d = edst[e];
        int pos = atomicAdd(&cursor[d], 1);
        eidx[offsets[d] + pos] = esrc[e];
    }
}

// ---------------- layer 1: h1 = relu(GCN(one_hot(x), W1, b1)) ----------------
// one_hot(x) @ W1 == row gather W1[x[i]]

__global__ __launch_bounds__(256) void k_layer1(
        const int* __restrict__ x, const int* __restrict__ offsets,
        const int* __restrict__ eidx, const float* __restrict__ dinv,
        const void* __restrict__ W1, const void* __restrict__ b1,
        const int* __restrict__ flag, float* __restrict__ h1) {
    __shared__ int   sxs[64];
    __shared__ float sdv[64];
    bool f32 = (*flag != 0);
    int i = blockIdx.x;
    int t = threadIdx.x;
    int beg = offsets[i], end = offsets[i + 1];
    float acc = 0.f;
    for (int chunk = beg; chunk < end; chunk += 64) {
        int m = min(64, end - chunk);
        __syncthreads();
        if (t < m) {
            int s = eidx[chunk + t];
            sxs[t] = x[s];
            sdv[t] = dinv[s];
        }
        __syncthreads();
        for (int q = 0; q < m; ++q)
            acc += sdv[q] * ldf(W1, sxs[q] * HH + t, f32);
    }
    float di = dinv[i];
    acc = di * acc + di * di * ldf(W1, x[i] * HH + t, f32) + ldf(b1, t, f32);
    h1[i * HH + t] = fmaxf(acc, 0.f);
}

// ---------------- layer 2 part A: agg2 = A_norm @ h1 ----------------

__global__ __launch_bounds__(256) void k_agg2(
        const int* __restrict__ offsets, const int* __restrict__ eidx,
        const float* __restrict__ dinv, const float* __restrict__ h1,
        float* __restrict__ agg2) {
    __shared__ int   sss[64];
    __shared__ float sdv[64];
    int i = blockIdx.x;
    int t = threadIdx.x;
    int beg = offsets[i], end = offsets[i + 1];
    float acc = 0.f;
    for (int chunk = beg; chunk < end; chunk += 64) {
        int m = min(64, end - chunk);
        __syncthreads();
        if (t < m) {
            int s = eidx[chunk + t];
            sss[t] = s;
            sdv[t] = dinv[s];
        }
        __syncthreads();
        for (int q = 0; q < m; ++q)
            acc += sdv[q] * h1[sss[q] * HH + t];
    }
    float di = dinv[i];
    agg2[i * HH + t] = di * acc + di * di * h1[i * HH + t];
}

// ---------------- layer 2 part B: h2 = relu(agg2 @ W2 + b2) ----------------
// 32 rows x 256 cols per block; per thread 8 rows x 4 cols register tile.

__global__ __launch_bounds__(256) void k_gemm2(
        const float* __restrict__ A, const void* __restrict__ W2,
        const void* __restrict__ b2, const int* __restrict__ flag,
        float* __restrict__ Y) {
    __shared__ float As[32][257];
    bool f32 = (*flag != 0);
    int t = threadIdx.x;
    int r0 = blockIdx.x * 32;
    for (int idx = t; idx < 32 * 256; idx += 256) {
        int r = idx >> 8, k = idx & 255;
        int row = r0 + r;
        As[r][k] = (row < NN) ? A[row * HH + k] : 0.f;
    }
    __syncthreads();
    int c0 = t & 63;
    int rg = t >> 6;
    float acc[8][4];
#pragma unroll
    for (int rr = 0; rr < 8; ++rr)
#pragma unroll
        for (int j = 0; j < 4; ++j) acc[rr][j] = 0.f;

    if (f32) {
        const float* W = (const float*)W2;
        for (int k = 0; k < 256; ++k) {
            float w0 = W[k * HH + c0];
            float w1 = W[k * HH + c0 + 64];
            float w2 = W[k * HH + c0 + 128];
            float w3 = W[k * HH + c0 + 192];
#pragma unroll
            for (int rr = 0; rr < 8; ++rr) {
                float a = As[rg * 8 + rr][k];
                acc[rr][0] += a * w0;
                acc[rr][1] += a * w1;
                acc[rr][2] += a * w2;
                acc[rr][3] += a * w3;
            }
        }
    } else {
        const bf16* W = (const bf16*)W2;
        for (int k = 0; k < 256; ++k) {
            float w0 = b2f(W[k * HH + c0]);
            float w1 = b2f(W[k * HH + c0 + 64]);
            float w2 = b2f(W[k * HH + c0 + 128]);
            float w3 = b2f(W[k * HH + c0 + 192]);
#pragma unroll
            for (int rr = 0; rr < 8; ++rr) {
                float a = As[rg * 8 + rr][k];
                acc[rr][0] += a * w0;
                acc[rr][1] += a * w1;
                acc[rr][2] += a * w2;
                acc[rr][3] += a * w3;
            }
        }
    }
    float bb0 = ldf(b2, c0,       f32);
    float bb1 = ldf(b2, c0 + 64,  f32);
    float bb2 = ldf(b2, c0 + 128, f32);
    float bb3 = ldf(b2, c0 + 192, f32);
#pragma unroll
    for (int rr = 0; rr < 8; ++rr) {
        int row = r0 + rg * 8 + rr;
        if (row < NN) {
            Y[row * HH + c0      ] = fmaxf(acc[rr][0] + bb0, 0.f);
            Y[row * HH + c0 + 64 ] = fmaxf(acc[rr][1] + bb1, 0.f);
            Y[row * HH + c0 + 128] = fmaxf(acc[rr][2] + bb2, 0.f);
            Y[row * HH + c0 + 192] = fmaxf(acc[rr][3] + bb3, 0.f);
        }
    }
}

// ---------------- score: per-node dots, then edge-sum of scalars ----------------

__global__ __launch_bounds__(256) void k_score_pre(
        const float* __restrict__ h2, const void* __restrict__ Wrel,
        const void* __restrict__ Wroot, const int* __restrict__ flag,
        float* __restrict__ trel, float* __restrict__ troot) {
    bool f32 = (*flag != 0);
    int node = blockIdx.x * 4 + (threadIdx.x >> 6);
    int lane = threadIdx.x & 63;
    float sr = 0.f, so = 0.f;
#pragma unroll
    for (int j = 0; j < 4; ++j) {
        int ch = lane + 64 * j;
        float v = h2[node * HH + ch];
        sr += v * ldf(Wrel, ch, f32);
        so += v * ldf(Wroot, ch, f32);
    }
#pragma unroll
    for (int off = 32; off > 0; off >>= 1) {
        sr += __shfl_down(sr, off, 64);
        so += __shfl_down(so, off, 64);
    }
    if (lane == 0) { trel[node] = sr; troot[node] = so; }
}

__global__ void k_score(const int* __restrict__ offsets, const int* __restrict__ eidx,
                        const float* __restrict__ trel, const float* __restrict__ troot,
                        const void* __restrict__ brel, const int* __restrict__ flag,
                        float* __restrict__ score) {
    int i = blockIdx.x * blockDim.x + threadIdx.x;
    if (i >= NN) return;
    bool f32 = (*flag != 0);
    float s = ldf(brel, 0, f32) + troot[i];
    int beg = offsets[i], end = offsets[i + 1];
    for (int p = beg; p < end; ++p) s += trel[eidx[p]];
    score[i] = s;
}

// ---------------- per-graph top-k (bitonic sort of 1024 in LDS) ----------------
// descending score, ties -> lower index first (matches jax.lax.top_k)

__global__ __launch_bounds__(512) void k_topk(const float* __restrict__ score,
                                              int* __restrict__ sel,
                                              float* __restrict__ selw) {
    __shared__ float s[1024];
    __shared__ int   id[1024];
    int b = blockIdx.x, t = threadIdx.x;
    for (int i = t; i < 1024; i += 512) {
        if (i < NPGc) { s[i] = score[b * NPGc + i]; id[i] = i; }
        else          { s[i] = -FLT_MAX;            id[i] = 0x7FFFFFFF; }
    }
    for (int k = 2; k <= 1024; k <<= 1) {
        for (int j = k >> 1; j > 0; j >>= 1) {
            __syncthreads();
            for (int i = t; i < 1024; i += 512) {
                int l = i ^ j;
                if (l > i) {
                    float si = s[i], sl = s[l];
                    int   ii = id[i], il = id[l];
                    bool iFirst = (si > sl) || (si == sl && ii < il);
                    bool doSwap = ((i & k) == 0) ? (!iFirst) : iFirst;
                    if (doSwap) { s[i] = sl; s[l] = si; id[i] = il; id[l] = ii; }
                }
            }
        }
    }
    __syncthreads();
    if (t < KK) {
        sel[b * KK + t]  = b * NPGc + id[t];
        selw[b * KK + t] = tanhf(s[t]);
    }
}

// ---------------- pooled = max over selected of h2[sel] * tanh(score) ----------------

__global__ __launch_bounds__(256) void k_pool(const float* __restrict__ h2,
                                              const int* __restrict__ sel,
                                              const float* __restrict__ selw,
                                              const int* __restrict__ flag,
                                              void* __restrict__ out) {
    __shared__ int   snode[256];
    __shared__ float sw[256];
    bool f32 = (*flag != 0);
    int b = blockIdx.x, t = threadIdx.x;
    float m = -FLT_MAX;
    for (int base = 0; base < KK; base += 256) {
        int cnt = min(256, KK - base);
        __syncthreads();
        if (t < cnt) {
            snode[t] = sel[b * KK + base + t];
            sw[t]    = selw[b * KK + base + t];
        }
        __syncthreads();
        for (int q = 0; q < cnt; ++q) {
            float v = h2[snode[q] * HH + t] * sw[q];
            m = fmaxf(m, v);
        }
    }
    if (f32) ((float*)out)[b * HH + t] = m;
    else     ((bf16*)out)[b * HH + t] = __float2bfloat16(m);
}

// ---------------- launch ----------------

extern "C" void kernel_launch(void* const* d_in, const int* in_sizes, int n_in,
                              void* d_out, int out_size, void* d_ws, size_t ws_size,
                              hipStream_t stream) {
    const int*  x    = (const int*)d_in[0];
    const int*  esrc = (const int*)d_in[1];
    const int*  edst = esrc + EE;
    const void* W1   = d_in[3];
    const void* b1   = d_in[4];
    const void* W2   = d_in[5];
    const void* b2   = d_in[6];
    const void* Wrel = d_in[7];
    const void* brel = d_in[8];
    const void* Wroot= d_in[9];

    char* w = (char*)d_ws;
    size_t off = 0;
    auto carve = [&](size_t bytes) -> void* {
        void* p = w + off;
        off = (off + bytes + 255) & ~(size_t)255;
        return p;
    };
    int*   flag    = (int*)  carve(256);
    int*   deg     = (int*)  carve((size_t)NN * 4);
    int*   partial = (int*)  carve((size_t)NN * 4);
    int*   bsums   = (int*)  carve(256 * 4);
    int*   offsets = (int*)  carve((size_t)(NN + 1) * 4);
    int*   cursor  = (int*)  carve((size_t)NN * 4);
    int*   eidx    = (int*)  carve((size_t)EE * 4);
    float* dinv    = (float*)carve((size_t)NN * 4);
    float* trel    = (float*)carve((size_t)NN * 4);
    float* troot   = (float*)carve((size_t)NN * 4);
    float* score   = (float*)carve((size_t)NN * 4);
    int*   sel     = (int*)  carve((size_t)BB * KK * 4);
    float* selw    = (float*)carve((size_t)BB * KK * 4);
    float* bufA    = (float*)carve((size_t)NN * HH * 4);  // h1, then h2
    float* bufB    = (float*)carve((size_t)NN * HH * 4);  // agg2
    (void)ws_size; (void)in_sizes; (void)n_in; (void)out_size;

    const int NB = (NN + 255) / 256;       // 196
    const int EBLK = (EE + 255) / 256;     // 1172

    k_detect    <<<1, 256, 0, stream>>>((const unsigned int*)W1, flag);
    k_init      <<<NB, 256, 0, stream>>>(deg, cursor);
    k_count     <<<EBLK, 256, 0, stream>>>(edst, deg);
    k_scan_block<<<NB, 256, 0, stream>>>(deg, partial, bsums);
    k_scan_sums <<<1, 256, 0, stream>>>(bsums, NB);
    k_finalize  <<<NB, 256, 0, stream>>>(deg, partial, bsums, offsets, dinv);
    k_fill      <<<EBLK, 256, 0, stream>>>(esrc, edst, offsets, cursor, eidx);

    k_layer1    <<<NN, 256, 0, stream>>>(x, offsets, eidx, dinv, W1, b1, flag, bufA);
    k_agg2      <<<NN, 256, 0, stream>>>(offsets, eidx, dinv, bufA, bufB);
    k_gemm2     <<<(NN + 31) / 32, 256, 0, stream>>>(bufB, W2, b2, flag, bufA);

    k_score_pre <<<NN / 4, 256, 0, stream>>>(bufA, Wrel, Wroot, flag, trel, troot);
    k_score     <<<NB, 256, 0, stream>>>(offsets, eidx, trel, troot, brel, flag, score);
    k_topk      <<<BB, 512, 0, stream>>>(score, sel, selw);
    k_pool      <<<BB, 256, 0, stream>>>(bufA, sel, selw, flag, out_size ? d_out : d_out);
}

// Round 4
// 427.871 us; speedup vs baseline: 1.1360x; 1.1360x over previous
//
#include <hip/hip_runtime.h>
#include <hip/hip_bf16.h>
#include <float.h>
#include <math.h>

#define NN   50000
#define BB   50
#define NPGc 1000
#define EE   300000
#define HH   256
#define FIN  79
#define KK   500

typedef __hip_bfloat16 bf16;

__device__ __forceinline__ float b2f(bf16 v) { return __bfloat162float(v); }
__device__ __forceinline__ float bfbits(unsigned short h) {
    return __uint_as_float(((unsigned int)h) << 16);
}

// Runtime-dtype scalar load: f32 ? fp32 buffer : packed bf16 buffer.
__device__ __forceinline__ float ldf(const void* p, int i, bool f32) {
    return f32 ? ((const float*)p)[i] : bfbits(((const unsigned short*)p)[i]);
}
// 4 consecutive elements, i multiple of 4.
__device__ __forceinline__ float4 ldf4(const void* p, int i, bool f32) {
    if (f32) return ((const float4*)p)[i >> 2];
    ushort4 u = ((const ushort4*)p)[i >> 2];
    return make_float4(bfbits(u.x), bfbits(u.y), bfbits(u.z), bfbits(u.w));
}

// ---------------- dtype detection ----------------
// First 10112 uint32 words of W1 (40448 B; safe for both dtype layouts).
// bf16-packed: low half is a real |w|<1 weight -> exponent < 128.
// fp32: low 16 bits are mantissa noise -> "exponent" >= 128 half the time.
__global__ void k_detect(const unsigned int* __restrict__ w1, int* __restrict__ flag) {
    __shared__ int sm[256];
    int t = threadIdx.x;
    int c = 0;
    for (int i = t; i < 10112; i += 256) {
        unsigned int e = (w1[i] >> 7) & 0xFFu;
        c += (e >= 128u) ? 1 : 0;
    }
    sm[t] = c;
    __syncthreads();
    for (int off = 128; off > 0; off >>= 1) {
        if (t < off) sm[t] += sm[t + off];
        __syncthreads();
    }
    if (t == 0) flag[0] = (sm[0] > 500) ? 1 : 0;
}

// ---------------- degree / CSR construction ----------------

__global__ void k_init(int* __restrict__ deg, int* __restrict__ cursor) {
    int i = blockIdx.x * blockDim.x + threadIdx.x;
    if (i < NN) { deg[i] = 0; cursor[i] = 0; }
}

__global__ void k_count(const int* __restrict__ edst, int* __restrict__ deg) {
    int e = blockIdx.x * blockDim.x + threadIdx.x;
    if (e < EE) atomicAdd(&deg[edst[e]], 1);
}

__global__ void k_scan_block(const int* __restrict__ deg, int* __restrict__ partial,
                             int* __restrict__ bsums) {
    __shared__ int sm[256];
    int t = threadIdx.x;
    int i = blockIdx.x * 256 + t;
    int v = (i < NN) ? deg[i] : 0;
    sm[t] = v;
    __syncthreads();
    for (int off = 1; off < 256; off <<= 1) {
        int u = (t >= off) ? sm[t - off] : 0;
        __syncthreads();
        sm[t] += u;
        __syncthreads();
    }
    if (i < NN) partial[i] = sm[t];
    if (t == 255) bsums[blockIdx.x] = sm[255];
}

__global__ void k_scan_sums(int* __restrict__ bsums, int nb) {
    __shared__ int sm[256];
    int t = threadIdx.x;
    int v = (t < nb) ? bsums[t] : 0;
    sm[t] = v;
    __syncthreads();
    for (int off = 1; off < 256; off <<= 1) {
        int u = (t >= off) ? sm[t - off] : 0;
        __syncthreads();
        sm[t] += u;
        __syncthreads();
    }
    if (t < nb) bsums[t] = sm[t];
}

__global__ void k_finalize(const int* __restrict__ deg, const int* __restrict__ partial,
                           const int* __restrict__ bsums, int* __restrict__ offsets,
                           float* __restrict__ dinv) {
    int b = blockIdx.x;
    int i = b * 256 + threadIdx.x;
    if (i >= NN) return;
    int incl = partial[i] + (b ? bsums[b - 1] : 0);
    offsets[i] = incl - deg[i];
    if (i == NN - 1) offsets[NN] = incl;
    dinv[i] = rsqrtf((float)(deg[i] + 1));   // +1 self-loop
}

__global__ void k_fill(const int* __restrict__ esrc, const int* __restrict__ edst,
                       const int* __restrict__ offsets, int* __restrict__ cursor,
                       int* __restrict__ eidx) {
    int e = blockIdx.x * blockDim.x + threadIdx.x;
    if (e < EE) {
        int d = edst[e];
        int pos = atomicAdd(&cursor[d], 1);
        eidx[offsets[d] + pos] = esrc[e];
    }
}

// ---------------- layer 1: h1 = relu(GCN(one_hot(x), W1, b1)) ----------------
// one_hot(x)@W1 == row gather W1[x[i]]. Wave-per-node, float4 per lane.

__global__ __launch_bounds__(256) void k_layer1(
        const int* __restrict__ x, const int* __restrict__ offsets,
        const int* __restrict__ eidx, const float* __restrict__ dinv,
        const void* __restrict__ W1, const void* __restrict__ b1,
        const int* __restrict__ flag, float* __restrict__ h1) {
    bool f32 = (*flag != 0);
    int node = blockIdx.x * 4 + (threadIdx.x >> 6);
    int lane = threadIdx.x & 63;
    int ch = lane * 4;
    if (node >= NN) return;
    int beg = offsets[node], end = offsets[node + 1];
    float4 acc = make_float4(0.f, 0.f, 0.f, 0.f);
    for (int p = beg; p < end; ++p) {
        int s = eidx[p];
        float dv = dinv[s];
        float4 w = ldf4(W1, x[s] * HH + ch, f32);
        acc.x += dv * w.x; acc.y += dv * w.y; acc.z += dv * w.z; acc.w += dv * w.w;
    }
    float di = dinv[node];
    float d2 = di * di;
    float4 ws = ldf4(W1, x[node] * HH + ch, f32);
    float4 bb = ldf4(b1, ch, f32);
    float4 o;
    o.x = fmaxf(di * acc.x + d2 * ws.x + bb.x, 0.f);
    o.y = fmaxf(di * acc.y + d2 * ws.y + bb.y, 0.f);
    o.z = fmaxf(di * acc.z + d2 * ws.z + bb.z, 0.f);
    o.w = fmaxf(di * acc.w + d2 * ws.w + bb.w, 0.f);
    ((float4*)h1)[(node * HH + ch) >> 2] = o;
}

// ---------------- layer 2 part A: agg2 = A_norm @ h1 ----------------
// Wave-per-node, float4 gathers; XCD swizzle for h1 L2 locality.
// Bijection: 12500 = 8*1562 + 4. First 12496 blocks -> 8 contiguous ranges
// of 1562 groups (one per XCD); last 4 blocks -> identity tail. (Round-3 bug:
// (b&7)*1563+(b>>3) skipped grps 7814/9377/10940 -> 12 nodes unwritten.)

__global__ __launch_bounds__(256) void k_agg2(
        const int* __restrict__ offsets, const int* __restrict__ eidx,
        const float* __restrict__ dinv, const float* __restrict__ h1,
        float* __restrict__ agg2) {
    int b = blockIdx.x;
    int grp = (b < 12496) ? ((b & 7) * 1562 + (b >> 3)) : b;
    int node = grp * 4 + (threadIdx.x >> 6);
    int lane = threadIdx.x & 63;
    int ch = lane * 4;
    if (node >= NN) return;
    int beg = offsets[node], end = offsets[node + 1];
    float4 acc = make_float4(0.f, 0.f, 0.f, 0.f);
    for (int p = beg; p < end; ++p) {
        int s = eidx[p];
        float dv = dinv[s];
        float4 v = ((const float4*)h1)[(s * HH + ch) >> 2];
        acc.x += dv * v.x; acc.y += dv * v.y; acc.z += dv * v.z; acc.w += dv * v.w;
    }
    float di = dinv[node];
    float d2 = di * di;
    float4 v = ((const float4*)h1)[(node * HH + ch) >> 2];
    float4 o;
    o.x = di * acc.x + d2 * v.x;
    o.y = di * acc.y + d2 * v.y;
    o.z = di * acc.z + d2 * v.z;
    o.w = di * acc.w + d2 * v.w;
    ((float4*)agg2)[(node * HH + ch) >> 2] = o;
}

// ---------------- layer 2 part B: h2 = relu(agg2 @ W2 + b2) + fused scorer dots ----
// 32 rows x 256 cols per block; thread: 8 rows x 4 consecutive cols; k unroll 4.
// Epilogue also produces trel = h2 . Wrel, troot = h2 . Wroot per row.

__global__ __launch_bounds__(256) void k_gemm2(
        const float* __restrict__ A, const void* __restrict__ W2,
        const void* __restrict__ b2, const void* __restrict__ Wrel,
        const void* __restrict__ Wroot, const int* __restrict__ flag,
        float* __restrict__ Y, float* __restrict__ trel, float* __restrict__ troot) {
    __shared__ float As[32][260];
    bool f32 = (*flag != 0);
    int t = threadIdx.x;
    int r0 = blockIdx.x * 32;
    int c4 = (t & 63);          // float4 column index: cols 4*c4 .. 4*c4+3
    int rg = t >> 6;            // wave id -> rows rg*8 .. rg*8+7

    // stage A tile (32 rows x 256 cols) as float4
    {
        int r = rg;             // rows rg, rg+4, ..., rg+28
#pragma unroll
        for (int j = 0; j < 8; ++j, r += 4) {
            int row = r0 + r;
            float4 v = (row < NN) ? ((const float4*)A)[(row * HH) / 4 + c4]
                                  : make_float4(0.f, 0.f, 0.f, 0.f);
            *(float4*)&As[r][c4 * 4] = v;
        }
    }
    __syncthreads();

    float4 acc[8];
#pragma unroll
    for (int rr = 0; rr < 8; ++rr) acc[rr] = make_float4(0.f, 0.f, 0.f, 0.f);

    if (f32) {
        const float* W = (const float*)W2;
        for (int k = 0; k < 256; k += 4) {
            float4 w0 = *(const float4*)&W[(k + 0) * HH + c4 * 4];
            float4 w1 = *(const float4*)&W[(k + 1) * HH + c4 * 4];
            float4 w2 = *(const float4*)&W[(k + 2) * HH + c4 * 4];
            float4 w3 = *(const float4*)&W[(k + 3) * HH + c4 * 4];
#pragma unroll
            for (int rr = 0; rr < 8; ++rr) {
                float4 a = *(const float4*)&As[rg * 8 + rr][k];
                acc[rr].x += a.x * w0.x + a.y * w1.x + a.z * w2.x + a.w * w3.x;
                acc[rr].y += a.x * w0.y + a.y * w1.y + a.z * w2.y + a.w * w3.y;
                acc[rr].z += a.x * w0.z + a.y * w1.z + a.z * w2.z + a.w * w3.z;
                acc[rr].w += a.x * w0.w + a.y * w1.w + a.z * w2.w + a.w * w3.w;
            }
        }
    } else {
        const unsigned short* W = (const unsigned short*)W2;
        for (int k = 0; k < 256; k += 4) {
            ushort4 u0 = *(const ushort4*)&W[(k + 0) * HH + c4 * 4];
            ushort4 u1 = *(const ushort4*)&W[(k + 1) * HH + c4 * 4];
            ushort4 u2 = *(const ushort4*)&W[(k + 2) * HH + c4 * 4];
            ushort4 u3 = *(const ushort4*)&W[(k + 3) * HH + c4 * 4];
            float4 w0 = make_float4(bfbits(u0.x), bfbits(u0.y), bfbits(u0.z), bfbits(u0.w));
            float4 w1 = make_float4(bfbits(u1.x), bfbits(u1.y), bfbits(u1.z), bfbits(u1.w));
            float4 w2 = make_float4(bfbits(u2.x), bfbits(u2.y), bfbits(u2.z), bfbits(u2.w));
            float4 w3 = make_float4(bfbits(u3.x), bfbits(u3.y), bfbits(u3.z), bfbits(u3.w));
#pragma unroll
            for (int rr = 0; rr < 8; ++rr) {
                float4 a = *(const float4*)&As[rg * 8 + rr][k];
                acc[rr].x += a.x * w0.x + a.y * w1.x + a.z * w2.x + a.w * w3.x;
                acc[rr].y += a.x * w0.y + a.y * w1.y + a.z * w2.y + a.w * w3.y;
                acc[rr].z += a.x * w0.z + a.y * w1.z + a.z * w2.z + a.w * w3.z;
                acc[rr].w += a.x * w0.w + a.y * w1.w + a.z * w2.w + a.w * w3.w;
            }
        }
    }

    float4 bb = ldf4(b2, c4 * 4, f32);
    float4 wr = ldf4(Wrel, c4 * 4, f32);
    float4 wo = ldf4(Wroot, c4 * 4, f32);
#pragma unroll
    for (int rr = 0; rr < 8; ++rr) {
        int row = r0 + rg * 8 + rr;
        float4 y;
        y.x = fmaxf(acc[rr].x + bb.x, 0.f);
        y.y = fmaxf(acc[rr].y + bb.y, 0.f);
        y.z = fmaxf(acc[rr].z + bb.z, 0.f);
        y.w = fmaxf(acc[rr].w + bb.w, 0.f);
        if (row < NN)
            ((float4*)Y)[(row * HH) / 4 + c4] = y;
        float sr = y.x * wr.x + y.y * wr.y + y.z * wr.z + y.w * wr.w;
        float so = y.x * wo.x + y.y * wo.y + y.z * wo.z + y.w * wo.w;
#pragma unroll
        for (int off = 32; off > 0; off >>= 1) {
            sr += __shfl_xor(sr, off, 64);
            so += __shfl_xor(so, off, 64);
        }
        if ((t & 63) == 0 && row < NN) { trel[row] = sr; troot[row] = so; }
    }
}

// ---------------- score = brel + troot[i] + sum_in trel[s] ----------------

__global__ void k_score(const int* __restrict__ offsets, const int* __restrict__ eidx,
                        const float* __restrict__ trel, const float* __restrict__ troot,
                        const void* __restrict__ brel, const int* __restrict__ flag,
                        float* __restrict__ score) {
    int i = blockIdx.x * blockDim.x + threadIdx.x;
    if (i >= NN) return;
    bool f32 = (*flag != 0);
    float s = ldf(brel, 0, f32) + troot[i];
    int beg = offsets[i], end = offsets[i + 1];
    for (int p = beg; p < end; ++p) s += trel[eidx[p]];
    score[i] = s;
}

// ---------------- per-graph top-k (bitonic sort of 1024 in LDS) ----------------
// descending score, ties -> lower index (matches jax.lax.top_k)

__global__ __launch_bounds__(512) void k_topk(const float* __restrict__ score,
                                              int* __restrict__ sel,
                                              float* __restrict__ selw) {
    __shared__ float s[1024];
    __shared__ int   id[1024];
    int b = blockIdx.x, t = threadIdx.x;
    for (int i = t; i < 1024; i += 512) {
        if (i < NPGc) { s[i] = score[b * NPGc + i]; id[i] = i; }
        else          { s[i] = -FLT_MAX;            id[i] = 0x7FFFFFFF; }
    }
    for (int k = 2; k <= 1024; k <<= 1) {
        for (int j = k >> 1; j > 0; j >>= 1) {
            __syncthreads();
            for (int i = t; i < 1024; i += 512) {
                int l = i ^ j;
                if (l > i) {
                    float si = s[i], sl = s[l];
                    int   ii = id[i], il = id[l];
                    bool iFirst = (si > sl) || (si == sl && ii < il);
                    bool doSwap = ((i & k) == 0) ? (!iFirst) : iFirst;
                    if (doSwap) { s[i] = sl; s[l] = si; id[i] = il; id[l] = ii; }
                }
            }
        }
    }
    __syncthreads();
    if (t < KK) {
        sel[b * KK + t]  = b * NPGc + id[t];
        selw[b * KK + t] = tanhf(s[t]);
    }
}

// ---------------- pooled = max over selected of h2[sel] * tanh(score) ----------------

__global__ __launch_bounds__(256) void k_pool(const float* __restrict__ h2,
                                              const int* __restrict__ sel,
                                              const float* __restrict__ selw,
                                              const int* __restrict__ flag,
                                              void* __restrict__ out) {
    __shared__ int   snode[256];
    __shared__ float sw[256];
    bool f32 = (*flag != 0);
    int b = blockIdx.x, t = threadIdx.x;
    float m = -FLT_MAX;
    for (int base = 0; base < KK; base += 256) {
        int cnt = min(256, KK - base);
        __syncthreads();
        if (t < cnt) {
            snode[t] = sel[b * KK + base + t];
            sw[t]    = selw[b * KK + base + t];
        }
        __syncthreads();
        for (int q = 0; q < cnt; ++q) {
            float v = h2[snode[q] * HH + t] * sw[q];
            m = fmaxf(m, v);
        }
    }
    if (f32) ((float*)out)[b * HH + t] = m;
    else     ((bf16*)out)[b * HH + t] = __float2bfloat16(m);
}

// ---------------- launch ----------------

extern "C" void kernel_launch(void* const* d_in, const int* in_sizes, int n_in,
                              void* d_out, int out_size, void* d_ws, size_t ws_size,
                              hipStream_t stream) {
    const int*  x    = (const int*)d_in[0];
    const int*  esrc = (const int*)d_in[1];
    const int*  edst = esrc + EE;
    const void* W1   = d_in[3];
    const void* b1   = d_in[4];
    const void* W2   = d_in[5];
    const void* b2   = d_in[6];
    const void* Wrel = d_in[7];
    const void* brel = d_in[8];
    const void* Wroot= d_in[9];

    char* w = (char*)d_ws;
    size_t off = 0;
    auto carve = [&](size_t bytes) -> void* {
        void* p = w + off;
        off = (off + bytes + 255) & ~(size_t)255;
        return p;
    };
    int*   flag    = (int*)  carve(256);
    int*   deg     = (int*)  carve((size_t)NN * 4);
    int*   partial = (int*)  carve((size_t)NN * 4);
    int*   bsums   = (int*)  carve(256 * 4);
    int*   offsets = (int*)  carve((size_t)(NN + 1) * 4);
    int*   cursor  = (int*)  carve((size_t)NN * 4);
    int*   eidx    = (int*)  carve((size_t)EE * 4);
    float* dinv    = (float*)carve((size_t)NN * 4);
    float* trel    = (float*)carve((size_t)NN * 4);
    float* troot   = (float*)carve((size_t)NN * 4);
    float* score   = (float*)carve((size_t)NN * 4);
    int*   sel     = (int*)  carve((size_t)BB * KK * 4);
    float* selw    = (float*)carve((size_t)BB * KK * 4);
    float* bufA    = (float*)carve((size_t)NN * HH * 4);  // h1, then h2
    float* bufB    = (float*)carve((size_t)NN * HH * 4);  // agg2
    (void)ws_size; (void)in_sizes; (void)n_in; (void)out_size;

    const int NB = (NN + 255) / 256;       // 196
    const int EBLK = (EE + 255) / 256;     // 1172
    const int NGB = (NN + 3) / 4;          // wave-per-node blocks: 12500

    k_detect    <<<1, 256, 0, stream>>>((const unsigned int*)W1, flag);
    k_init      <<<NB, 256, 0, stream>>>(deg, cursor);
    k_count     <<<EBLK, 256, 0, stream>>>(edst, deg);
    k_scan_block<<<NB, 256, 0, stream>>>(deg, partial, bsums);
    k_scan_sums <<<1, 256, 0, stream>>>(bsums, NB);
    k_finalize  <<<NB, 256, 0, stream>>>(deg, partial, bsums, offsets, dinv);
    k_fill      <<<EBLK, 256, 0, stream>>>(esrc, edst, offsets, cursor, eidx);

    k_layer1    <<<NGB, 256, 0, stream>>>(x, offsets, eidx, dinv, W1, b1, flag, bufA);
    k_agg2      <<<NGB, 256, 0, stream>>>(offsets, eidx, dinv, bufA, bufB);
    k_gemm2     <<<(NN + 31) / 32, 256, 0, stream>>>(bufB, W2, b2, Wrel, Wroot, flag,
                                                     bufA, trel, troot);

    k_score     <<<NB, 256, 0, stream>>>(offsets, eidx, trel, troot, brel, flag, score);
    k_topk      <<<BB, 512, 0, stream>>>(score, sel, selw);
    k_pool      <<<BB, 256, 0, stream>>>(bufA, sel, selw, flag, d_out);
}

// Round 6
// 419.973 us; speedup vs baseline: 1.1574x; 1.0188x over previous
//
#include <hip/hip_runtime.h>
#include <hip/hip_bf16.h>
#include <float.h>
#include <math.h>

#define NN   50000
#define BB   50
#define NPGc 1000
#define EE   300000
#define HH   256
#define FIN  79
#define KK   500
#define GR   32      // gemm rows per block
#define KC   64      // gemm k-chunk

typedef __hip_bfloat16 bf16;

__device__ __forceinline__ float bfbits(unsigned short h) {
    return __uint_as_float(((unsigned int)h) << 16);
}
__device__ __forceinline__ float ldf(const void* p, int i, bool f32) {
    return f32 ? ((const float*)p)[i] : bfbits(((const unsigned short*)p)[i]);
}
__device__ __forceinline__ float4 ldf4(const void* p, int i, bool f32) {
    if (f32) return ((const float4*)p)[i >> 2];
    ushort4 u = ((const ushort4*)p)[i >> 2];
    return make_float4(bfbits(u.x), bfbits(u.y), bfbits(u.z), bfbits(u.w));
}

// ---------------- count (+ dtype detect in the extra block) ----------------
// detect: first 10112 uint32 of W1 (40448 B, safe in both layouts). bf16-packed:
// low half is |w|<1 -> exp<128. fp32: low 16 bits are mantissa noise -> exp>=128
// about half the time.

__global__ void k_count(const int* __restrict__ edst, int* __restrict__ deg,
                        const unsigned int* __restrict__ w1, int* __restrict__ flag) {
    int t = threadIdx.x;
    if (blockIdx.x == gridDim.x - 1) {
        __shared__ int sm[256];
        int c = 0;
        for (int i = t; i < 10112; i += 256) {
            unsigned int e = (w1[i] >> 7) & 0xFFu;
            c += (e >= 128u) ? 1 : 0;
        }
        sm[t] = c;
        __syncthreads();
        for (int off = 128; off > 0; off >>= 1) {
            if (t < off) sm[t] += sm[t + off];
            __syncthreads();
        }
        if (t == 0) flag[0] = (sm[0] > 500) ? 1 : 0;
        return;
    }
    int e = blockIdx.x * 256 + t;
    if (e < EE) atomicAdd(&deg[edst[e]], 1);
}

// ---------------- CSR scan ----------------

__global__ void k_scan_block(const int* __restrict__ deg, int* __restrict__ partial,
                             int* __restrict__ bsums) {
    __shared__ int sm[256];
    int t = threadIdx.x;
    int i = blockIdx.x * 256 + t;
    int v = (i < NN) ? deg[i] : 0;
    sm[t] = v;
    __syncthreads();
    for (int off = 1; off < 256; off <<= 1) {
        int u = (t >= off) ? sm[t - off] : 0;
        __syncthreads();
        sm[t] += u;
        __syncthreads();
    }
    if (i < NN) partial[i] = sm[t];
    if (t == 255) bsums[blockIdx.x] = sm[255];
}

// finalize, with inline reduction of bsums[0..b) (grid=196 <= 256 threads)
__global__ void k_finalize(const int* __restrict__ deg, const int* __restrict__ partial,
                           const int* __restrict__ bsums, int* __restrict__ offsets,
                           float* __restrict__ dinv) {
    __shared__ int sm[256];
    int b = blockIdx.x;
    int t = threadIdx.x;
    sm[t] = (t < b) ? bsums[t] : 0;
    __syncthreads();
    for (int off = 128; off > 0; off >>= 1) {
        if (t < off) sm[t] += sm[t + off];
        __syncthreads();
    }
    int base = sm[0];
    int i = b * 256 + t;
    if (i >= NN) return;
    int incl = partial[i] + base;
    offsets[i] = incl - deg[i];
    if (i == NN - 1) offsets[NN] = incl;
    dinv[i] = rsqrtf((float)(deg[i] + 1));   // +1 self-loop
}

__global__ void k_fill(const int* __restrict__ esrc, const int* __restrict__ edst,
                       const int* __restrict__ offsets, int* __restrict__ cursor,
                       int* __restrict__ eidx) {
    int e = blockIdx.x * blockDim.x + threadIdx.x;
    if (e < EE) {
        int d = edst[e];
        int pos = atomicAdd(&cursor[d], 1);
        eidx[offsets[d] + pos] = esrc[e];
    }
}

// ---------------- layer 1: h1 = relu(GCN(one_hot(x), W1, b1)) ----------------

__global__ __launch_bounds__(256) void k_layer1(
        const int* __restrict__ x, const int* __restrict__ offsets,
        const int* __restrict__ eidx, const float* __restrict__ dinv,
        const void* __restrict__ W1, const void* __restrict__ b1,
        const int* __restrict__ flag, float* __restrict__ h1) {
    bool f32 = (*flag != 0);
    int node = blockIdx.x * 4 + (threadIdx.x >> 6);
    int lane = threadIdx.x & 63;
    int ch = lane * 4;
    if (node >= NN) return;
    int beg = offsets[node], end = offsets[node + 1];
    float4 acc = make_float4(0.f, 0.f, 0.f, 0.f);
    for (int p = beg; p < end; ++p) {
        int s = eidx[p];
        float dv = dinv[s];
        float4 w = ldf4(W1, x[s] * HH + ch, f32);
        acc.x += dv * w.x; acc.y += dv * w.y; acc.z += dv * w.z; acc.w += dv * w.w;
    }
    float di = dinv[node];
    float d2 = di * di;
    float4 ws = ldf4(W1, x[node] * HH + ch, f32);
    float4 bb = ldf4(b1, ch, f32);
    float4 o;
    o.x = fmaxf(di * acc.x + d2 * ws.x + bb.x, 0.f);
    o.y = fmaxf(di * acc.y + d2 * ws.y + bb.y, 0.f);
    o.z = fmaxf(di * acc.z + d2 * ws.z + bb.z, 0.f);
    o.w = fmaxf(di * acc.w + d2 * ws.w + bb.w, 0.f);
    ((float4*)h1)[(node * HH + ch) >> 2] = o;
}

// ---------------- agg2 = A_norm @ h1 (wave-per-node, XCD-swizzled) ----------------
// Bijection: 12500 = 8*1562 + 4; first 12496 -> 8 contiguous per-XCD ranges, tail id.

__global__ __launch_bounds__(256) void k_agg2(
        const int* __restrict__ offsets, const int* __restrict__ eidx,
        const float* __restrict__ dinv, const float* __restrict__ h1,
        float* __restrict__ agg2) {
    int b = blockIdx.x;
    int grp = (b < 12496) ? ((b & 7) * 1562 + (b >> 3)) : b;
    int node = grp * 4 + (threadIdx.x >> 6);
    int lane = threadIdx.x & 63;
    int ch = lane * 4;
    if (node >= NN) return;
    int beg = offsets[node], end = offsets[node + 1];
    float4 acc = make_float4(0.f, 0.f, 0.f, 0.f);
    for (int p = beg; p < end; ++p) {
        int s = eidx[p];
        float dv = dinv[s];
        float4 v = ((const float4*)h1)[(s * HH + ch) >> 2];
        acc.x += dv * v.x; acc.y += dv * v.y; acc.z += dv * v.z; acc.w += dv * v.w;
    }
    float di = dinv[node];
    float d2 = di * di;
    float4 v = ((const float4*)h1)[(node * HH + ch) >> 2];
    float4 o;
    o.x = di * acc.x + d2 * v.x;
    o.y = di * acc.y + d2 * v.y;
    o.z = di * acc.z + d2 * v.z;
    o.w = di * acc.w + d2 * v.w;
    ((float4*)agg2)[(node * HH + ch) >> 2] = o;
}

// ---------------- h2 = relu(agg2 @ W2 + b2) + fused scorer dots ----------------
// 128 threads: c32 = t&31 (cols 4c32..+3 and 128+4c32..+3), rg = t>>5 (8 rows).
// K chunked (KC=64) into LDS; A-frag reads are half-wave-uniform broadcasts.

__global__ __launch_bounds__(128) void k_gemm2(
        const float* __restrict__ A, const void* __restrict__ W2,
        const void* __restrict__ b2, const void* __restrict__ Wrel,
        const void* __restrict__ Wroot, const int* __restrict__ flag,
        float* __restrict__ Y, float* __restrict__ trel, float* __restrict__ troot) {
    __shared__ float As[GR][KC + 4];
    bool f32 = (*flag != 0);
    int t = threadIdx.x;
    int c32 = t & 31;
    int rg  = t >> 5;
    int r0 = blockIdx.x * GR;
    int colA = c32 * 4;
    int colB = 128 + c32 * 4;

    float4 acc0[8], acc1[8];
#pragma unroll
    for (int rr = 0; rr < 8; ++rr) {
        acc0[rr] = make_float4(0.f, 0.f, 0.f, 0.f);
        acc1[rr] = make_float4(0.f, 0.f, 0.f, 0.f);
    }

    for (int kc = 0; kc < HH; kc += KC) {
        __syncthreads();
        // stage A chunk: GR x KC = 512 float4, 4 per thread
#pragma unroll
        for (int j = 0; j < 4; ++j) {
            int i = t + j * 128;
            int r = i >> 4;            // 16 float4 per row
            int c = (i & 15) * 4;
            int row = r0 + r;
            float4 v = (row < NN) ? *(const float4*)&A[row * HH + kc + c]
                                  : make_float4(0.f, 0.f, 0.f, 0.f);
            *(float4*)&As[r][c] = v;
        }
        __syncthreads();

        if (f32) {
            const float* W = (const float*)W2;
            for (int kk = 0; kk < KC; kk += 4) {
                int kg = kc + kk;
                float4 w0a = *(const float4*)&W[(kg + 0) * HH + colA];
                float4 w0b = *(const float4*)&W[(kg + 0) * HH + colB];
                float4 w1a = *(const float4*)&W[(kg + 1) * HH + colA];
                float4 w1b = *(const float4*)&W[(kg + 1) * HH + colB];
                float4 w2a = *(const float4*)&W[(kg + 2) * HH + colA];
                float4 w2b = *(const float4*)&W[(kg + 2) * HH + colB];
                float4 w3a = *(const float4*)&W[(kg + 3) * HH + colA];
                float4 w3b = *(const float4*)&W[(kg + 3) * HH + colB];
#pragma unroll
                for (int rr = 0; rr < 8; ++rr) {
                    float4 a = *(const float4*)&As[rg * 8 + rr][kk];
                    acc0[rr].x += a.x * w0a.x + a.y * w1a.x + a.z * w2a.x + a.w * w3a.x;
                    acc0[rr].y += a.x * w0a.y + a.y * w1a.y + a.z * w2a.y + a.w * w3a.y;
                    acc0[rr].z += a.x * w0a.z + a.y * w1a.z + a.z * w2a.z + a.w * w3a.z;
                    acc0[rr].w += a.x * w0a.w + a.y * w1a.w + a.z * w2a.w + a.w * w3a.w;
                    acc1[rr].x += a.x * w0b.x + a.y * w1b.x + a.z * w2b.x + a.w * w3b.x;
                    acc1[rr].y += a.x * w0b.y + a.y * w1b.y + a.z * w2b.y + a.w * w3b.y;
                    acc1[rr].z += a.x * w0b.z + a.y * w1b.z + a.z * w2b.z + a.w * w3b.z;
                    acc1[rr].w += a.x * w0b.w + a.y * w1b.w + a.z * w2b.w + a.w * w3b.w;
                }
            }
        } else {
            const unsigned short* W = (const unsigned short*)W2;
            for (int kk = 0; kk < KC; kk += 4) {
                int kg = kc + kk;
                ushort4 u0a = *(const ushort4*)&W[(kg + 0) * HH + colA];
                ushort4 u0b = *(const ushort4*)&W[(kg + 0) * HH + colB];
                ushort4 u1a = *(const ushort4*)&W[(kg + 1) * HH + colA];
                ushort4 u1b = *(const ushort4*)&W[(kg + 1) * HH + colB];
                ushort4 u2a = *(const ushort4*)&W[(kg + 2) * HH + colA];
                ushort4 u2b = *(const ushort4*)&W[(kg + 2) * HH + colB];
                ushort4 u3a = *(const ushort4*)&W[(kg + 3) * HH + colA];
                ushort4 u3b = *(const ushort4*)&W[(kg + 3) * HH + colB];
                float4 w0a = make_float4(bfbits(u0a.x), bfbits(u0a.y), bfbits(u0a.z), bfbits(u0a.w));
                float4 w0b = make_float4(bfbits(u0b.x), bfbits(u0b.y), bfbits(u0b.z), bfbits(u0b.w));
                float4 w1a = make_float4(bfbits(u1a.x), bfbits(u1a.y), bfbits(u1a.z), bfbits(u1a.w));
                float4 w1b = make_float4(bfbits(u1b.x), bfbits(u1b.y), bfbits(u1b.z), bfbits(u1b.w));
                float4 w2a = make_float4(bfbits(u2a.x), bfbits(u2a.y), bfbits(u2a.z), bfbits(u2a.w));
                float4 w2b = make_float4(bfbits(u2b.x), bfbits(u2b.y), bfbits(u2b.z), bfbits(u2b.w));
                float4 w3a = make_float4(bfbits(u3a.x), bfbits(u3a.y), bfbits(u3a.z), bfbits(u3a.w));
                float4 w3b = make_float4(bfbits(u3b.x), bfbits(u3b.y), bfbits(u3b.z), bfbits(u3b.w));
#pragma unroll
                for (int rr = 0; rr < 8; ++rr) {
                    float4 a = *(const float4*)&As[rg * 8 + rr][kk];
                    acc0[rr].x += a.x * w0a.x + a.y * w1a.x + a.z * w2a.x + a.w * w3a.x;
                    acc0[rr].y += a.x * w0a.y + a.y * w1a.y + a.z * w2a.y + a.w * w3a.y;
                    acc0[rr].z += a.x * w0a.z + a.y * w1a.z + a.z * w2a.z + a.w * w3a.z;
                    acc0[rr].w += a.x * w0a.w + a.y * w1a.w + a.z * w2a.w + a.w * w3a.w;
                    acc1[rr].x += a.x * w0b.x + a.y * w1b.x + a.z * w2b.x + a.w * w3b.x;
                    acc1[rr].y += a.x * w0b.y + a.y * w1b.y + a.z * w2b.y + a.w * w3b.y;
                    acc1[rr].z += a.x * w0b.z + a.y * w1b.z + a.z * w2b.z + a.w * w3b.z;
                    acc1[rr].w += a.x * w0b.w + a.y * w1b.w + a.z * w2b.w + a.w * w3b.w;
                }
            }
        }
    }

    float4 bbA = ldf4(b2, colA, f32),   bbB = ldf4(b2, colB, f32);
    float4 wrA = ldf4(Wrel, colA, f32), wrB = ldf4(Wrel, colB, f32);
    float4 woA = ldf4(Wroot, colA, f32), woB = ldf4(Wroot, colB, f32);
#pragma unroll
    for (int rr = 0; rr < 8; ++rr) {
        int row = r0 + rg * 8 + rr;
        float4 y0, y1;
        y0.x = fmaxf(acc0[rr].x + bbA.x, 0.f);
        y0.y = fmaxf(acc0[rr].y + bbA.y, 0.f);
        y0.z = fmaxf(acc0[rr].z + bbA.z, 0.f);
        y0.w = fmaxf(acc0[rr].w + bbA.w, 0.f);
        y1.x = fmaxf(acc1[rr].x + bbB.x, 0.f);
        y1.y = fmaxf(acc1[rr].y + bbB.y, 0.f);
        y1.z = fmaxf(acc1[rr].z + bbB.z, 0.f);
        y1.w = fmaxf(acc1[rr].w + bbB.w, 0.f);
        if (row < NN) {
            *(float4*)&Y[row * HH + colA] = y0;
            *(float4*)&Y[row * HH + colB] = y1;
        }
        float sr = y0.x * wrA.x + y0.y * wrA.y + y0.z * wrA.z + y0.w * wrA.w
                 + y1.x * wrB.x + y1.y * wrB.y + y1.z * wrB.z + y1.w * wrB.w;
        float so = y0.x * woA.x + y0.y * woA.y + y0.z * woA.z + y0.w * woA.w
                 + y1.x * woB.x + y1.y * woB.y + y1.z * woB.z + y1.w * woB.w;
#pragma unroll
        for (int off = 16; off > 0; off >>= 1) {
            sr += __shfl_xor(sr, off, 32);
            so += __shfl_xor(so, off, 32);
        }
        if (c32 == 0 && row < NN) { trel[row] = sr; troot[row] = so; }
    }
}

// ---------------- fused: score -> per-graph top-k -> tanh-weighted max-pool ------
// One block per graph, 512 threads. Scores computed into LDS, bitonic sort of
// 1024 (desc score, asc index = jax.lax.top_k tie-break), then pooled max.

__global__ __launch_bounds__(512) void k_topk(
        const int* __restrict__ offsets, const int* __restrict__ eidx,
        const float* __restrict__ trel, const float* __restrict__ troot,
        const void* __restrict__ brel, const int* __restrict__ flag,
        const float* __restrict__ h2, void* __restrict__ out) {
    __shared__ float s[1024];
    __shared__ int   id[1024];
    __shared__ float sw[KK];
    __shared__ int   snode[KK];
    bool f32 = (*flag != 0);
    int b = blockIdx.x, t = threadIdx.x;
    float br = ldf(brel, 0, f32);
    for (int i = t; i < 1024; i += 512) {
        if (i < NPGc) {
            int node = b * NPGc + i;
            float sc = br + troot[node];
            int beg = offsets[node], end = offsets[node + 1];
            for (int p = beg; p < end; ++p) sc += trel[eidx[p]];
            s[i] = sc; id[i] = i;
        } else { s[i] = -FLT_MAX; id[i] = 0x7FFFFFFF; }
    }
    for (int k = 2; k <= 1024; k <<= 1) {
        for (int j = k >> 1; j > 0; j >>= 1) {
            __syncthreads();
            for (int i = t; i < 1024; i += 512) {
                int l = i ^ j;
                if (l > i) {
                    float si = s[i], sl = s[l];
                    int   ii = id[i], il = id[l];
                    bool iFirst = (si > sl) || (si == sl && ii < il);
                    bool doSwap = ((i & k) == 0) ? (!iFirst) : iFirst;
                    if (doSwap) { s[i] = sl; s[l] = si; id[i] = il; id[l] = ii; }
                }
            }
        }
    }
    __syncthreads();
    if (t < KK) {
        snode[t] = b * NPGc + id[t];
        sw[t]    = tanhf(s[t]);
    }
    __syncthreads();
    // pool: col = t&255, half = t>>8 handles 250 selected rows
    int col = t & 255;
    int half = t >> 8;
    float m = -FLT_MAX;
    for (int q = half * 250; q < half * 250 + 250; ++q) {
        float v = h2[snode[q] * HH + col] * sw[q];
        m = fmaxf(m, v);
    }
    __syncthreads();          // s[] reuse
    s[half * 256 + col] = m;
    __syncthreads();
    if (t < 256) {
        float r = fmaxf(s[t], s[256 + t]);
        if (f32) ((float*)out)[b * HH + t] = r;
        else     ((bf16*)out)[b * HH + t] = __float2bfloat16(r);
    }
}

// ---------------- launch ----------------

extern "C" void kernel_launch(void* const* d_in, const int* in_sizes, int n_in,
                              void* d_out, int out_size, void* d_ws, size_t ws_size,
                              hipStream_t stream) {
    const int*  x    = (const int*)d_in[0];
    const int*  esrc = (const int*)d_in[1];
    const int*  edst = esrc + EE;
    const void* W1   = d_in[3];
    const void* b1   = d_in[4];
    const void* W2   = d_in[5];
    const void* b2   = d_in[6];
    const void* Wrel = d_in[7];
    const void* brel = d_in[8];
    const void* Wroot= d_in[9];

    char* w = (char*)d_ws;
    size_t off = 0;
    auto carve = [&](size_t bytes) -> void* {
        void* p = w + off;
        off = (off + bytes + 255) & ~(size_t)255;
        return p;
    };
    int*   flag    = (int*)  carve(256);
    int*   deg     = (int*)  carve((size_t)2 * NN * 4); // deg + cursor in ONE
    int*   cursor  = deg + NN;                          // carve: memset covers both
    int*   partial = (int*)  carve((size_t)NN * 4);
    int*   bsums   = (int*)  carve(256 * 4);
    int*   offsets = (int*)  carve((size_t)(NN + 1) * 4);
    int*   eidx    = (int*)  carve((size_t)EE * 4);
    float* dinv    = (float*)carve((size_t)NN * 4);
    float* trel    = (float*)carve((size_t)NN * 4);
    float* troot   = (float*)carve((size_t)NN * 4);
    float* bufA    = (float*)carve((size_t)NN * HH * 4);  // h1, then h2
    float* bufB    = (float*)carve((size_t)NN * HH * 4);  // agg2
    (void)ws_size; (void)in_sizes; (void)n_in; (void)out_size;

    const int NB   = (NN + 255) / 256;     // 196
    const int EBLK = (EE + 255) / 256;     // 1172
    const int NGB  = (NN + 3) / 4;         // 12500

    hipMemsetAsync(deg, 0, (size_t)2 * NN * 4, stream);  // deg + cursor exactly
    k_count     <<<EBLK + 1, 256, 0, stream>>>(edst, deg, (const unsigned int*)W1, flag);
    k_scan_block<<<NB, 256, 0, stream>>>(deg, partial, bsums);
    k_finalize  <<<NB, 256, 0, stream>>>(deg, partial, bsums, offsets, dinv);
    k_fill      <<<EBLK, 256, 0, stream>>>(esrc, edst, offsets, cursor, eidx);

    k_layer1    <<<NGB, 256, 0, stream>>>(x, offsets, eidx, dinv, W1, b1, flag, bufA);
    k_agg2      <<<NGB, 256, 0, stream>>>(offsets, eidx, dinv, bufA, bufB);
    k_gemm2     <<<(NN + GR - 1) / GR, 128, 0, stream>>>(bufB, W2, b2, Wrel, Wroot,
                                                         flag, bufA, trel, troot);
    k_topk      <<<BB, 512, 0, stream>>>(offsets, eidx, trel, troot, brel, flag,
                                         bufA, d_out);
}

// Round 7
// 377.387 us; speedup vs baseline: 1.2880x; 1.1128x over previous
//
#include <hip/hip_runtime.h>
#include <hip/hip_bf16.h>
#include <float.h>
#include <math.h>

#define NN   50000
#define BB   50
#define NPGc 1000
#define EE   300000
#define HH   256
#define FIN  79
#define KK   500
#define GR   64      // gemm rows per block
#define KC   32      // gemm k-chunk

typedef __hip_bfloat16 bf16;

__device__ __forceinline__ float bfbits(unsigned short h) {
    return __uint_as_float(((unsigned int)h) << 16);
}
__device__ __forceinline__ float ldf(const void* p, int i, bool f32) {
    return f32 ? ((const float*)p)[i] : bfbits(((const unsigned short*)p)[i]);
}
__device__ __forceinline__ float4 ldf4(const void* p, int i, bool f32) {
    if (f32) return ((const float4*)p)[i >> 2];
    ushort4 u = ((const ushort4*)p)[i >> 2];
    return make_float4(bfbits(u.x), bfbits(u.y), bfbits(u.z), bfbits(u.w));
}

// ---------------- count (+ dtype detect in the extra block) ----------------
// detect: first 10112 uint32 of W1 (40448 B, safe in both layouts). bf16-packed:
// low half is |w|<1 -> exp<128. fp32: low 16 bits are mantissa noise -> exp>=128
// about half the time.

__global__ void k_count(const int* __restrict__ edst, int* __restrict__ deg,
                        const unsigned int* __restrict__ w1, int* __restrict__ flag) {
    int t = threadIdx.x;
    if (blockIdx.x == gridDim.x - 1) {
        __shared__ int sm[256];
        int c = 0;
        for (int i = t; i < 10112; i += 256) {
            unsigned int e = (w1[i] >> 7) & 0xFFu;
            c += (e >= 128u) ? 1 : 0;
        }
        sm[t] = c;
        __syncthreads();
        for (int off = 128; off > 0; off >>= 1) {
            if (t < off) sm[t] += sm[t + off];
            __syncthreads();
        }
        if (t == 0) flag[0] = (sm[0] > 500) ? 1 : 0;
        return;
    }
    int e = blockIdx.x * 256 + t;
    if (e < EE) atomicAdd(&deg[edst[e]], 1);
}

// ---------------- CSR scan ----------------

__global__ void k_scan_block(const int* __restrict__ deg, int* __restrict__ partial,
                             int* __restrict__ bsums) {
    __shared__ int sm[256];
    int t = threadIdx.x;
    int i = blockIdx.x * 256 + t;
    int v = (i < NN) ? deg[i] : 0;
    sm[t] = v;
    __syncthreads();
    for (int off = 1; off < 256; off <<= 1) {
        int u = (t >= off) ? sm[t - off] : 0;
        __syncthreads();
        sm[t] += u;
        __syncthreads();
    }
    if (i < NN) partial[i] = sm[t];
    if (t == 255) bsums[blockIdx.x] = sm[255];
}

// finalize, with inline reduction of bsums[0..b) (grid=196 <= 256 threads)
__global__ void k_finalize(const int* __restrict__ deg, const int* __restrict__ partial,
                           const int* __restrict__ bsums, int* __restrict__ offsets,
                           float* __restrict__ dinv) {
    __shared__ int sm[256];
    int b = blockIdx.x;
    int t = threadIdx.x;
    sm[t] = (t < b) ? bsums[t] : 0;
    __syncthreads();
    for (int off = 128; off > 0; off >>= 1) {
        if (t < off) sm[t] += sm[t + off];
        __syncthreads();
    }
    int base = sm[0];
    int i = b * 256 + t;
    if (i >= NN) return;
    int incl = partial[i] + base;
    offsets[i] = incl - deg[i];
    if (i == NN - 1) offsets[NN] = incl;
    dinv[i] = rsqrtf((float)(deg[i] + 1));   // +1 self-loop
}

__global__ void k_fill(const int* __restrict__ esrc, const int* __restrict__ edst,
                       const int* __restrict__ offsets, int* __restrict__ cursor,
                       int* __restrict__ eidx) {
    int e = blockIdx.x * blockDim.x + threadIdx.x;
    if (e < EE) {
        int d = edst[e];
        int pos = atomicAdd(&cursor[d], 1);
        eidx[offsets[d] + pos] = esrc[e];
    }
}

// ---------------- layer 1: h1 = relu(GCN(one_hot(x), W1, b1)) ----------------

__global__ __launch_bounds__(256) void k_layer1(
        const int* __restrict__ x, const int* __restrict__ offsets,
        const int* __restrict__ eidx, const float* __restrict__ dinv,
        const void* __restrict__ W1, const void* __restrict__ b1,
        const int* __restrict__ flag, float* __restrict__ h1) {
    bool f32 = (*flag != 0);
    int node = blockIdx.x * 4 + (threadIdx.x >> 6);
    int lane = threadIdx.x & 63;
    int ch = lane * 4;
    if (node >= NN) return;
    int beg = offsets[node], end = offsets[node + 1];
    float4 acc = make_float4(0.f, 0.f, 0.f, 0.f);
    for (int p = beg; p < end; ++p) {
        int s = eidx[p];
        float dv = dinv[s];
        float4 w = ldf4(W1, x[s] * HH + ch, f32);
        acc.x += dv * w.x; acc.y += dv * w.y; acc.z += dv * w.z; acc.w += dv * w.w;
    }
    float di = dinv[node];
    float d2 = di * di;
    float4 ws = ldf4(W1, x[node] * HH + ch, f32);
    float4 bb = ldf4(b1, ch, f32);
    float4 o;
    o.x = fmaxf(di * acc.x + d2 * ws.x + bb.x, 0.f);
    o.y = fmaxf(di * acc.y + d2 * ws.y + bb.y, 0.f);
    o.z = fmaxf(di * acc.z + d2 * ws.z + bb.z, 0.f);
    o.w = fmaxf(di * acc.w + d2 * ws.w + bb.w, 0.f);
    ((float4*)h1)[(node * HH + ch) >> 2] = o;
}

// ---------------- agg2 = A_norm @ h1 (wave-per-node, XCD-swizzled) ----------------
// Bijection: 12500 = 8*1562 + 4; first 12496 -> 8 contiguous per-XCD ranges, tail id.

__global__ __launch_bounds__(256) void k_agg2(
        const int* __restrict__ offsets, const int* __restrict__ eidx,
        const float* __restrict__ dinv, const float* __restrict__ h1,
        float* __restrict__ agg2) {
    int b = blockIdx.x;
    int grp = (b < 12496) ? ((b & 7) * 1562 + (b >> 3)) : b;
    int node = grp * 4 + (threadIdx.x >> 6);
    int lane = threadIdx.x & 63;
    int ch = lane * 4;
    if (node >= NN) return;
    int beg = offsets[node], end = offsets[node + 1];
    float4 acc = make_float4(0.f, 0.f, 0.f, 0.f);
    for (int p = beg; p < end; ++p) {
        int s = eidx[p];
        float dv = dinv[s];
        float4 v = ((const float4*)h1)[(s * HH + ch) >> 2];
        acc.x += dv * v.x; acc.y += dv * v.y; acc.z += dv * v.z; acc.w += dv * v.w;
    }
    float di = dinv[node];
    float d2 = di * di;
    float4 v = ((const float4*)h1)[(node * HH + ch) >> 2];
    float4 o;
    o.x = di * acc.x + d2 * v.x;
    o.y = di * acc.y + d2 * v.y;
    o.z = di * acc.z + d2 * v.z;
    o.w = di * acc.w + d2 * v.w;
    ((float4*)agg2)[(node * HH + ch) >> 2] = o;
}

// ---------------- h2 = relu(agg2 @ W2 + b2) + fused scorer dots ----------------
// 256 threads, 64 rows x 256 cols per block. Both A-chunk (64x32) and W2-chunk
// (32x256) staged in LDS (40960 B total -> exactly 4 blocks/CU). Per thread:
// 8 rows (rg=t>>5) x 8 cols (colA/colB = 4*(t&31), +128). Inner loop is pure
// fp32 FMA + LDS broadcasts; dtype conversion happens once at staging.

__global__ __launch_bounds__(256, 4) void k_gemm2(
        const float* __restrict__ A, const void* __restrict__ W2,
        const void* __restrict__ b2, const void* __restrict__ Wrel,
        const void* __restrict__ Wroot, const int* __restrict__ flag,
        float* __restrict__ Y, float* __restrict__ trel, float* __restrict__ troot) {
    __shared__ float As[GR][KC];     // 8 KB
    __shared__ float Ws[KC][HH];     // 32 KB
    bool f32 = (*flag != 0);
    int t = threadIdx.x;
    int c32 = t & 31;
    int rg  = t >> 5;
    int r0 = blockIdx.x * GR;
    int colA = c32 * 4;
    int colB = 128 + colA;

    float4 acc0[8], acc1[8];
#pragma unroll
    for (int rr = 0; rr < 8; ++rr) {
        acc0[rr] = make_float4(0.f, 0.f, 0.f, 0.f);
        acc1[rr] = make_float4(0.f, 0.f, 0.f, 0.f);
    }

    for (int kc = 0; kc < HH; kc += KC) {
        __syncthreads();
        // stage A chunk: 64x32 = 512 float4, 2 per thread
#pragma unroll
        for (int j = 0; j < 2; ++j) {
            int i = t + j * 256;
            int r = i >> 3;
            int c = (i & 7) * 4;
            int row = r0 + r;
            float4 v = (row < NN) ? *(const float4*)&A[row * HH + kc + c]
                                  : make_float4(0.f, 0.f, 0.f, 0.f);
            *(float4*)&As[r][c] = v;
        }
        // stage W chunk: 32x256 = 2048 float4, 8 per thread (convert if bf16)
#pragma unroll
        for (int j = 0; j < 8; ++j) {
            int i = t + j * 256;
            int kk = i >> 6;
            int c = (i & 63) * 4;
            float4 v = ldf4(W2, (kc + kk) * HH + c, f32);
            *(float4*)&Ws[kk][c] = v;
        }
        __syncthreads();

        for (int kk = 0; kk < KC; kk += 4) {
            float4 w0a = *(const float4*)&Ws[kk + 0][colA];
            float4 w0b = *(const float4*)&Ws[kk + 0][colB];
            float4 w1a = *(const float4*)&Ws[kk + 1][colA];
            float4 w1b = *(const float4*)&Ws[kk + 1][colB];
            float4 w2a = *(const float4*)&Ws[kk + 2][colA];
            float4 w2b = *(const float4*)&Ws[kk + 2][colB];
            float4 w3a = *(const float4*)&Ws[kk + 3][colA];
            float4 w3b = *(const float4*)&Ws[kk + 3][colB];
#pragma unroll
            for (int rr = 0; rr < 8; ++rr) {
                float4 a = *(const float4*)&As[rg * 8 + rr][kk];
                acc0[rr].x += a.x * w0a.x + a.y * w1a.x + a.z * w2a.x + a.w * w3a.x;
                acc0[rr].y += a.x * w0a.y + a.y * w1a.y + a.z * w2a.y + a.w * w3a.y;
                acc0[rr].z += a.x * w0a.z + a.y * w1a.z + a.z * w2a.z + a.w * w3a.z;
                acc0[rr].w += a.x * w0a.w + a.y * w1a.w + a.z * w2a.w + a.w * w3a.w;
                acc1[rr].x += a.x * w0b.x + a.y * w1b.x + a.z * w2b.x + a.w * w3b.x;
                acc1[rr].y += a.x * w0b.y + a.y * w1b.y + a.z * w2b.y + a.w * w3b.y;
                acc1[rr].z += a.x * w0b.z + a.y * w1b.z + a.z * w2b.z + a.w * w3b.z;
                acc1[rr].w += a.x * w0b.w + a.y * w1b.w + a.z * w2b.w + a.w * w3b.w;
            }
        }
    }

    float4 bbA = ldf4(b2, colA, f32),    bbB = ldf4(b2, colB, f32);
    float4 wrA = ldf4(Wrel, colA, f32),  wrB = ldf4(Wrel, colB, f32);
    float4 woA = ldf4(Wroot, colA, f32), woB = ldf4(Wroot, colB, f32);
#pragma unroll
    for (int rr = 0; rr < 8; ++rr) {
        int row = r0 + rg * 8 + rr;
        float4 y0, y1;
        y0.x = fmaxf(acc0[rr].x + bbA.x, 0.f);
        y0.y = fmaxf(acc0[rr].y + bbA.y, 0.f);
        y0.z = fmaxf(acc0[rr].z + bbA.z, 0.f);
        y0.w = fmaxf(acc0[rr].w + bbA.w, 0.f);
        y1.x = fmaxf(acc1[rr].x + bbB.x, 0.f);
        y1.y = fmaxf(acc1[rr].y + bbB.y, 0.f);
        y1.z = fmaxf(acc1[rr].z + bbB.z, 0.f);
        y1.w = fmaxf(acc1[rr].w + bbB.w, 0.f);
        if (row < NN) {
            *(float4*)&Y[row * HH + colA] = y0;
            *(float4*)&Y[row * HH + colB] = y1;
        }
        float sr = y0.x * wrA.x + y0.y * wrA.y + y0.z * wrA.z + y0.w * wrA.w
                 + y1.x * wrB.x + y1.y * wrB.y + y1.z * wrB.z + y1.w * wrB.w;
        float so = y0.x * woA.x + y0.y * woA.y + y0.z * woA.z + y0.w * woA.w
                 + y1.x * woB.x + y1.y * woB.y + y1.z * woB.z + y1.w * woB.w;
#pragma unroll
        for (int off = 16; off > 0; off >>= 1) {
            sr += __shfl_xor(sr, off, 32);
            so += __shfl_xor(so, off, 32);
        }
        if (c32 == 0 && row < NN) { trel[row] = sr; troot[row] = so; }
    }
}

// ---------------- fused: score -> per-graph top-k -> tanh-weighted max-pool ------
// One block per graph, 1024 threads (one bitonic element per thread).
// Desc score, asc index = jax.lax.top_k tie-break.

__global__ __launch_bounds__(1024) void k_topk(
        const int* __restrict__ offsets, const int* __restrict__ eidx,
        const float* __restrict__ trel, const float* __restrict__ troot,
        const void* __restrict__ brel, const int* __restrict__ flag,
        const float* __restrict__ h2, void* __restrict__ out) {
    __shared__ float s[1024];
    __shared__ int   id[1024];
    __shared__ float sw[KK];
    __shared__ int   snode[KK];
    bool f32 = (*flag != 0);
    int b = blockIdx.x, t = threadIdx.x;
    float br = ldf(brel, 0, f32);
    if (t < NPGc) {
        int node = b * NPGc + t;
        float sc = br + troot[node];
        int beg = offsets[node], end = offsets[node + 1];
        for (int p = beg; p < end; ++p) sc += trel[eidx[p]];
        s[t] = sc; id[t] = t;
    } else { s[t] = -FLT_MAX; id[t] = 0x7FFFFFFF; }
    for (int k = 2; k <= 1024; k <<= 1) {
        for (int j = k >> 1; j > 0; j >>= 1) {
            __syncthreads();
            int l = t ^ j;
            if (l > t) {
                float si = s[t], sl = s[l];
                int   ii = id[t], il = id[l];
                bool iFirst = (si > sl) || (si == sl && ii < il);
                bool doSwap = ((t & k) == 0) ? (!iFirst) : iFirst;
                if (doSwap) { s[t] = sl; s[l] = si; id[t] = il; id[l] = ii; }
            }
        }
    }
    __syncthreads();
    if (t < KK) {
        snode[t] = b * NPGc + id[t];
        sw[t]    = tanhf(s[t]);
    }
    __syncthreads();
    // pool: col = t&255, quarter = t>>8 handles 125 selected rows
    int col = t & 255;
    int q4 = t >> 8;
    float m = -FLT_MAX;
    for (int q = q4 * 125; q < q4 * 125 + 125; ++q) {
        float v = h2[snode[q] * HH + col] * sw[q];
        m = fmaxf(m, v);
    }
    __syncthreads();          // s[] reuse
    s[q4 * 256 + col] = m;
    __syncthreads();
    if (t < 256) {
        float r = fmaxf(fmaxf(s[t], s[256 + t]), fmaxf(s[512 + t], s[768 + t]));
        if (f32) ((float*)out)[b * HH + t] = r;
        else     ((bf16*)out)[b * HH + t] = __float2bfloat16(r);
    }
}

// ---------------- launch ----------------

extern "C" void kernel_launch(void* const* d_in, const int* in_sizes, int n_in,
                              void* d_out, int out_size, void* d_ws, size_t ws_size,
                              hipStream_t stream) {
    const int*  x    = (const int*)d_in[0];
    const int*  esrc = (const int*)d_in[1];
    const int*  edst = esrc + EE;
    const void* W1   = d_in[3];
    const void* b1   = d_in[4];
    const void* W2   = d_in[5];
    const void* b2   = d_in[6];
    const void* Wrel = d_in[7];
    const void* brel = d_in[8];
    const void* Wroot= d_in[9];

    char* w = (char*)d_ws;
    size_t off = 0;
    auto carve = [&](size_t bytes) -> void* {
        void* p = w + off;
        off = (off + bytes + 255) & ~(size_t)255;
        return p;
    };
    int*   flag    = (int*)  carve(256);
    int*   deg     = (int*)  carve((size_t)2 * NN * 4); // deg + cursor in ONE
    int*   cursor  = deg + NN;                          // carve: memset covers both
    int*   partial = (int*)  carve((size_t)NN * 4);
    int*   bsums   = (int*)  carve(256 * 4);
    int*   offsets = (int*)  carve((size_t)(NN + 1) * 4);
    int*   eidx    = (int*)  carve((size_t)EE * 4);
    float* dinv    = (float*)carve((size_t)NN * 4);
    float* trel    = (float*)carve((size_t)NN * 4);
    float* troot   = (float*)carve((size_t)NN * 4);
    float* bufA    = (float*)carve((size_t)NN * HH * 4);  // h1, then h2
    float* bufB    = (float*)carve((size_t)NN * HH * 4);  // agg2
    (void)ws_size; (void)in_sizes; (void)n_in; (void)out_size;

    const int NB   = (NN + 255) / 256;     // 196
    const int EBLK = (EE + 255) / 256;     // 1172
    const int NGB  = (NN + 3) / 4;         // 12500

    hipMemsetAsync(deg, 0, (size_t)2 * NN * 4, stream);  // deg + cursor exactly
    k_count     <<<EBLK + 1, 256, 0, stream>>>(edst, deg, (const unsigned int*)W1, flag);
    k_scan_block<<<NB, 256, 0, stream>>>(deg, partial, bsums);
    k_finalize  <<<NB, 256, 0, stream>>>(deg, partial, bsums, offsets, dinv);
    k_fill      <<<EBLK, 256, 0, stream>>>(esrc, edst, offsets, cursor, eidx);

    k_layer1    <<<NGB, 256, 0, stream>>>(x, offsets, eidx, dinv, W1, b1, flag, bufA);
    k_agg2      <<<NGB, 256, 0, stream>>>(offsets, eidx, dinv, bufA, bufB);
    k_gemm2     <<<(NN + GR - 1) / GR, 256, 0, stream>>>(bufB, W2, b2, Wrel, Wroot,
                                                         flag, bufA, trel, troot);
    k_topk      <<<BB, 1024, 0, stream>>>(offsets, eidx, trel, troot, brel, flag,
                                          bufA, d_out);
}

// Round 8
// 376.227 us; speedup vs baseline: 1.2920x; 1.0031x over previous
//
#include <hip/hip_runtime.h>
#include <hip/hip_bf16.h>
#include <float.h>
#include <math.h>

#define NN   50000
#define BB   50
#define NPGc 1000
#define EE   300000
#define HH   256
#define FIN  79
#define KK   500
#define GR   64      // gemm rows per block
#define KC   32      // gemm k-chunk

typedef __hip_bfloat16 bf16;

__device__ __forceinline__ float bfbits(unsigned short h) {
    return __uint_as_float(((unsigned int)h) << 16);
}
__device__ __forceinline__ float ldf(const void* p, int i, bool f32) {
    return f32 ? ((const float*)p)[i] : bfbits(((const unsigned short*)p)[i]);
}
__device__ __forceinline__ float4 ldf4(const void* p, int i, bool f32) {
    if (f32) return ((const float4*)p)[i >> 2];
    ushort4 u = ((const ushort4*)p)[i >> 2];
    return make_float4(bfbits(u.x), bfbits(u.y), bfbits(u.z), bfbits(u.w));
}

// ---------------- count (+ dtype detect in the extra block) ----------------
// detect: first 10112 uint32 of W1 (40448 B, safe in both layouts). bf16-packed:
// low half is |w|<1 -> exp<128. fp32: low 16 bits are mantissa noise -> exp>=128
// about half the time.

__global__ void k_count(const int* __restrict__ edst, int* __restrict__ deg,
                        const unsigned int* __restrict__ w1, int* __restrict__ flag) {
    int t = threadIdx.x;
    if (blockIdx.x == gridDim.x - 1) {
        __shared__ int sm[256];
        int c = 0;
        for (int i = t; i < 10112; i += 256) {
            unsigned int e = (w1[i] >> 7) & 0xFFu;
            c += (e >= 128u) ? 1 : 0;
        }
        sm[t] = c;
        __syncthreads();
        for (int off = 128; off > 0; off >>= 1) {
            if (t < off) sm[t] += sm[t + off];
            __syncthreads();
        }
        if (t == 0) flag[0] = (sm[0] > 500) ? 1 : 0;
        return;
    }
    int e = blockIdx.x * 256 + t;
    if (e < EE) atomicAdd(&deg[edst[e]], 1);
}

// ---------------- CSR scan ----------------

__global__ void k_scan_block(const int* __restrict__ deg, int* __restrict__ partial,
                             int* __restrict__ bsums) {
    __shared__ int sm[256];
    int t = threadIdx.x;
    int i = blockIdx.x * 256 + t;
    int v = (i < NN) ? deg[i] : 0;
    sm[t] = v;
    __syncthreads();
    for (int off = 1; off < 256; off <<= 1) {
        int u = (t >= off) ? sm[t - off] : 0;
        __syncthreads();
        sm[t] += u;
        __syncthreads();
    }
    if (i < NN) partial[i] = sm[t];
    if (t == 255) bsums[blockIdx.x] = sm[255];
}

// finalize, with inline reduction of bsums[0..b) (grid=196 <= 256 threads)
__global__ void k_finalize(const int* __restrict__ deg, const int* __restrict__ partial,
                           const int* __restrict__ bsums, int* __restrict__ offsets,
                           float* __restrict__ dinv) {
    __shared__ int sm[256];
    int b = blockIdx.x;
    int t = threadIdx.x;
    sm[t] = (t < b) ? bsums[t] : 0;
    __syncthreads();
    for (int off = 128; off > 0; off >>= 1) {
        if (t < off) sm[t] += sm[t + off];
        __syncthreads();
    }
    int base = sm[0];
    int i = b * 256 + t;
    if (i >= NN) return;
    int incl = partial[i] + base;
    offsets[i] = incl - deg[i];
    if (i == NN - 1) offsets[NN] = incl;
    dinv[i] = rsqrtf((float)(deg[i] + 1));   // +1 self-loop
}

__global__ void k_fill(const int* __restrict__ esrc, const int* __restrict__ edst,
                       const int* __restrict__ offsets, int* __restrict__ cursor,
                       int* __restrict__ eidx) {
    int e = blockIdx.x * blockDim.x + threadIdx.x;
    if (e < EE) {
        int d = edst[e];
        int pos = atomicAdd(&cursor[d], 1);
        eidx[offsets[d] + pos] = esrc[e];
    }
}

// ---------------- layer 1: h1 = relu(GCN(one_hot(x), W1, b1)) ----------------

__global__ __launch_bounds__(256) void k_layer1(
        const int* __restrict__ x, const int* __restrict__ offsets,
        const int* __restrict__ eidx, const float* __restrict__ dinv,
        const void* __restrict__ W1, const void* __restrict__ b1,
        const int* __restrict__ flag, float* __restrict__ h1) {
    bool f32 = (*flag != 0);
    int node = blockIdx.x * 4 + (threadIdx.x >> 6);
    int lane = threadIdx.x & 63;
    int ch = lane * 4;
    if (node >= NN) return;
    int beg = offsets[node], end = offsets[node + 1];
    float4 acc = make_float4(0.f, 0.f, 0.f, 0.f);
    for (int p = beg; p < end; ++p) {
        int s = eidx[p];
        float dv = dinv[s];
        float4 w = ldf4(W1, x[s] * HH + ch, f32);
        acc.x += dv * w.x; acc.y += dv * w.y; acc.z += dv * w.z; acc.w += dv * w.w;
    }
    float di = dinv[node];
    float d2 = di * di;
    float4 ws = ldf4(W1, x[node] * HH + ch, f32);
    float4 bb = ldf4(b1, ch, f32);
    float4 o;
    o.x = fmaxf(di * acc.x + d2 * ws.x + bb.x, 0.f);
    o.y = fmaxf(di * acc.y + d2 * ws.y + bb.y, 0.f);
    o.z = fmaxf(di * acc.z + d2 * ws.z + bb.z, 0.f);
    o.w = fmaxf(di * acc.w + d2 * ws.w + bb.w, 0.f);
    ((float4*)h1)[(node * HH + ch) >> 2] = o;
}

// ---------------- agg2 = A_norm @ h1 (wave-per-node, XCD-swizzled) ----------------
// Bijection: 12500 = 8*1562 + 4; first 12496 -> 8 contiguous per-XCD ranges, tail id.

__global__ __launch_bounds__(256) void k_agg2(
        const int* __restrict__ offsets, const int* __restrict__ eidx,
        const float* __restrict__ dinv, const float* __restrict__ h1,
        float* __restrict__ agg2) {
    int b = blockIdx.x;
    int grp = (b < 12496) ? ((b & 7) * 1562 + (b >> 3)) : b;
    int node = grp * 4 + (threadIdx.x >> 6);
    int lane = threadIdx.x & 63;
    int ch = lane * 4;
    if (node >= NN) return;
    int beg = offsets[node], end = offsets[node + 1];
    float4 acc = make_float4(0.f, 0.f, 0.f, 0.f);
    for (int p = beg; p < end; ++p) {
        int s = eidx[p];
        float dv = dinv[s];
        float4 v = ((const float4*)h1)[(s * HH + ch) >> 2];
        acc.x += dv * v.x; acc.y += dv * v.y; acc.z += dv * v.z; acc.w += dv * v.w;
    }
    float di = dinv[node];
    float d2 = di * di;
    float4 v = ((const float4*)h1)[(node * HH + ch) >> 2];
    float4 o;
    o.x = di * acc.x + d2 * v.x;
    o.y = di * acc.y + d2 * v.y;
    o.z = di * acc.z + d2 * v.z;
    o.w = di * acc.w + d2 * v.w;
    ((float4*)agg2)[(node * HH + ch) >> 2] = o;
}

// ---------------- h2 = relu(agg2 @ W2 + b2) + fused scorer dots ----------------
// 256 threads, 64 rows x 256 cols per block. W2 k-chunks (32x256 = 32 KB) in LDS;
// A fragments read DIRECTLY from global: each 32-lane group (rg = t>>5) reads the
// same 16 B address -> coalescer collapses to one L1/L2 transaction; per-chunk A
// working set ~8 KB -> L1-resident. LDS traffic per 4-k halves vs r7 (8 b128 W
// only, 0.75 B/MAC) -> VALU-issue-bound. Per thread: 8 rows x 8 cols.

__global__ __launch_bounds__(256, 3) void k_gemm2(
        const float* __restrict__ A, const void* __restrict__ W2,
        const void* __restrict__ b2, const void* __restrict__ Wrel,
        const void* __restrict__ Wroot, const int* __restrict__ flag,
        float* __restrict__ Y, float* __restrict__ trel, float* __restrict__ troot) {
    __shared__ float Ws[KC][HH];     // 32 KB
    bool f32 = (*flag != 0);
    int t = threadIdx.x;
    int c32 = t & 31;
    int rg  = t >> 5;
    int r0 = blockIdx.x * GR;
    int colA = c32 * 4;
    int colB = 128 + colA;

    // per-thread row fragment bases (clamped for the one partial tail block)
    int abase[8];
#pragma unroll
    for (int rr = 0; rr < 8; ++rr) {
        int row = r0 + rg * 8 + rr;
        abase[rr] = min(row, NN - 1) * (HH / 4);   // float4 index base
    }
    const float4* A4 = (const float4*)A;

    float4 acc0[8], acc1[8];
#pragma unroll
    for (int rr = 0; rr < 8; ++rr) {
        acc0[rr] = make_float4(0.f, 0.f, 0.f, 0.f);
        acc1[rr] = make_float4(0.f, 0.f, 0.f, 0.f);
    }

    for (int kc = 0; kc < HH; kc += KC) {
        __syncthreads();
        // stage W chunk: 32x256 = 2048 float4, 8 per thread (convert if bf16)
#pragma unroll
        for (int j = 0; j < 8; ++j) {
            int i = t + j * 256;
            int kk = i >> 6;
            int c = (i & 63) * 4;
            float4 v = ldf4(W2, (kc + kk) * HH + c, f32);
            *(float4*)&Ws[kk][c] = v;
        }
        __syncthreads();

        for (int kk = 0; kk < KC; kk += 4) {
            float4 w0a = *(const float4*)&Ws[kk + 0][colA];
            float4 w0b = *(const float4*)&Ws[kk + 0][colB];
            float4 w1a = *(const float4*)&Ws[kk + 1][colA];
            float4 w1b = *(const float4*)&Ws[kk + 1][colB];
            float4 w2a = *(const float4*)&Ws[kk + 2][colA];
            float4 w2b = *(const float4*)&Ws[kk + 2][colB];
            float4 w3a = *(const float4*)&Ws[kk + 3][colA];
            float4 w3b = *(const float4*)&Ws[kk + 3][colB];
            int kq = (kc + kk) >> 2;
#pragma unroll
            for (int rr = 0; rr < 8; ++rr) {
                float4 a = A4[abase[rr] + kq];
                acc0[rr].x += a.x * w0a.x + a.y * w1a.x + a.z * w2a.x + a.w * w3a.x;
                acc0[rr].y += a.x * w0a.y + a.y * w1a.y + a.z * w2a.y + a.w * w3a.y;
                acc0[rr].z += a.x * w0a.z + a.y * w1a.z + a.z * w2a.z + a.w * w3a.z;
                acc0[rr].w += a.x * w0a.w + a.y * w1a.w + a.z * w2a.w + a.w * w3a.w;
                acc1[rr].x += a.x * w0b.x + a.y * w1b.x + a.z * w2b.x + a.w * w3b.x;
                acc1[rr].y += a.x * w0b.y + a.y * w1b.y + a.z * w2b.y + a.w * w3b.y;
                acc1[rr].z += a.x * w0b.z + a.y * w1b.z + a.z * w2b.z + a.w * w3b.z;
                acc1[rr].w += a.x * w0b.w + a.y * w1b.w + a.z * w2b.w + a.w * w3b.w;
            }
        }
    }

    float4 bbA = ldf4(b2, colA, f32),    bbB = ldf4(b2, colB, f32);
    float4 wrA = ldf4(Wrel, colA, f32),  wrB = ldf4(Wrel, colB, f32);
    float4 woA = ldf4(Wroot, colA, f32), woB = ldf4(Wroot, colB, f32);
#pragma unroll
    for (int rr = 0; rr < 8; ++rr) {
        int row = r0 + rg * 8 + rr;
        float4 y0, y1;
        y0.x = fmaxf(acc0[rr].x + bbA.x, 0.f);
        y0.y = fmaxf(acc0[rr].y + bbA.y, 0.f);
        y0.z = fmaxf(acc0[rr].z + bbA.z, 0.f);
        y0.w = fmaxf(acc0[rr].w + bbA.w, 0.f);
        y1.x = fmaxf(acc1[rr].x + bbB.x, 0.f);
        y1.y = fmaxf(acc1[rr].y + bbB.y, 0.f);
        y1.z = fmaxf(acc1[rr].z + bbB.z, 0.f);
        y1.w = fmaxf(acc1[rr].w + bbB.w, 0.f);
        if (row < NN) {
            *(float4*)&Y[row * HH + colA] = y0;
            *(float4*)&Y[row * HH + colB] = y1;
        }
        float sr = y0.x * wrA.x + y0.y * wrA.y + y0.z * wrA.z + y0.w * wrA.w
                 + y1.x * wrB.x + y1.y * wrB.y + y1.z * wrB.z + y1.w * wrB.w;
        float so = y0.x * woA.x + y0.y * woA.y + y0.z * woA.z + y0.w * woA.w
                 + y1.x * woB.x + y1.y * woB.y + y1.z * woB.z + y1.w * woB.w;
#pragma unroll
        for (int off = 16; off > 0; off >>= 1) {
            sr += __shfl_xor(sr, off, 32);
            so += __shfl_xor(so, off, 32);
        }
        if (c32 == 0 && row < NN) { trel[row] = sr; troot[row] = so; }
    }
}

// ---------------- fused: score -> per-graph top-k -> tanh-weighted max-pool ------
// One block per graph, 1024 threads (one bitonic element per thread).
// Desc score, asc index = jax.lax.top_k tie-break.

__global__ __launch_bounds__(1024) void k_topk(
        const int* __restrict__ offsets, const int* __restrict__ eidx,
        const float* __restrict__ trel, const float* __restrict__ troot,
        const void* __restrict__ brel, const int* __restrict__ flag,
        const float* __restrict__ h2, void* __restrict__ out) {
    __shared__ float s[1024];
    __shared__ int   id[1024];
    __shared__ float sw[KK];
    __shared__ int   snode[KK];
    bool f32 = (*flag != 0);
    int b = blockIdx.x, t = threadIdx.x;
    float br = ldf(brel, 0, f32);
    if (t < NPGc) {
        int node = b * NPGc + t;
        float sc = br + troot[node];
        int beg = offsets[node], end = offsets[node + 1];
        for (int p = beg; p < end; ++p) sc += trel[eidx[p]];
        s[t] = sc; id[t] = t;
    } else { s[t] = -FLT_MAX; id[t] = 0x7FFFFFFF; }
    for (int k = 2; k <= 1024; k <<= 1) {
        for (int j = k >> 1; j > 0; j >>= 1) {
            __syncthreads();
            int l = t ^ j;
            if (l > t) {
                float si = s[t], sl = s[l];
                int   ii = id[t], il = id[l];
                bool iFirst = (si > sl) || (si == sl && ii < il);
                bool doSwap = ((t & k) == 0) ? (!iFirst) : iFirst;
                if (doSwap) { s[t] = sl; s[l] = si; id[t] = il; id[l] = ii; }
            }
        }
    }
    __syncthreads();
    if (t < KK) {
        snode[t] = b * NPGc + id[t];
        sw[t]    = tanhf(s[t]);
    }
    __syncthreads();
    // pool: col = t&255, quarter = t>>8 handles 125 selected rows
    int col = t & 255;
    int q4 = t >> 8;
    float m = -FLT_MAX;
    for (int q = q4 * 125; q < q4 * 125 + 125; ++q) {
        float v = h2[snode[q] * HH + col] * sw[q];
        m = fmaxf(m, v);
    }
    __syncthreads();          // s[] reuse
    s[q4 * 256 + col] = m;
    __syncthreads();
    if (t < 256) {
        float r = fmaxf(fmaxf(s[t], s[256 + t]), fmaxf(s[512 + t], s[768 + t]));
        if (f32) ((float*)out)[b * HH + t] = r;
        else     ((bf16*)out)[b * HH + t] = __float2bfloat16(r);
    }
}

// ---------------- launch ----------------

extern "C" void kernel_launch(void* const* d_in, const int* in_sizes, int n_in,
                              void* d_out, int out_size, void* d_ws, size_t ws_size,
                              hipStream_t stream) {
    const int*  x    = (const int*)d_in[0];
    const int*  esrc = (const int*)d_in[1];
    const int*  edst = esrc + EE;
    const void* W1   = d_in[3];
    const void* b1   = d_in[4];
    const void* W2   = d_in[5];
    const void* b2   = d_in[6];
    const void* Wrel = d_in[7];
    const void* brel = d_in[8];
    const void* Wroot= d_in[9];

    char* w = (char*)d_ws;
    size_t off = 0;
    auto carve = [&](size_t bytes) -> void* {
        void* p = w + off;
        off = (off + bytes + 255) & ~(size_t)255;
        return p;
    };
    int*   flag    = (int*)  carve(256);
    int*   deg     = (int*)  carve((size_t)2 * NN * 4); // deg + cursor in ONE
    int*   cursor  = deg + NN;                          // carve: memset covers both
    int*   partial = (int*)  carve((size_t)NN * 4);
    int*   bsums   = (int*)  carve(256 * 4);
    int*   offsets = (int*)  carve((size_t)(NN + 1) * 4);
    int*   eidx    = (int*)  carve((size_t)EE * 4);
    float* dinv    = (float*)carve((size_t)NN * 4);
    float* trel    = (float*)carve((size_t)NN * 4);
    float* troot   = (float*)carve((size_t)NN * 4);
    float* bufA    = (float*)carve((size_t)NN * HH * 4);  // h1, then h2
    float* bufB    = (float*)carve((size_t)NN * HH * 4);  // agg2
    (void)ws_size; (void)in_sizes; (void)n_in; (void)out_size;

    const int NB   = (NN + 255) / 256;     // 196
    const int EBLK = (EE + 255) / 256;     // 1172
    const int NGB  = (NN + 3) / 4;         // 12500

    hipMemsetAsync(deg, 0, (size_t)2 * NN * 4, stream);  // deg + cursor exactly
    k_count     <<<EBLK + 1, 256, 0, stream>>>(edst, deg, (const unsigned int*)W1, flag);
    k_scan_block<<<NB, 256, 0, stream>>>(deg, partial, bsums);
    k_finalize  <<<NB, 256, 0, stream>>>(deg, partial, bsums, offsets, dinv);
    k_fill      <<<EBLK, 256, 0, stream>>>(esrc, edst, offsets, cursor, eidx);

    k_layer1    <<<NGB, 256, 0, stream>>>(x, offsets, eidx, dinv, W1, b1, flag, bufA);
    k_agg2      <<<NGB, 256, 0, stream>>>(offsets, eidx, dinv, bufA, bufB);
    k_gemm2     <<<(NN + GR - 1) / GR, 256, 0, stream>>>(bufB, W2, b2, Wrel, Wroot,
                                                         flag, bufA, trel, troot);
    k_topk      <<<BB, 1024, 0, stream>>>(offsets, eidx, trel, troot, brel, flag,
                                          bufA, d_out);
}

// Round 9
// 337.326 us; speedup vs baseline: 1.4410x; 1.1153x over previous
//
#include <hip/hip_runtime.h>
#include <hip/hip_bf16.h>
#include <float.h>
#include <math.h>

#define NN   50000
#define BB   50
#define NPGc 1000
#define EE   300000
#define HH   256
#define FIN  79
#define KK   500
#define GR   32      // gemm rows per block

typedef __hip_bfloat16 bf16;

__device__ __forceinline__ float bfbits(unsigned short h) {
    return __uint_as_float(((unsigned int)h) << 16);
}
__device__ __forceinline__ float ldf(const void* p, int i, bool f32) {
    return f32 ? ((const float*)p)[i] : bfbits(((const unsigned short*)p)[i]);
}
__device__ __forceinline__ float4 ldf4(const void* p, int i, bool f32) {
    if (f32) return ((const float4*)p)[i >> 2];
    ushort4 u = ((const ushort4*)p)[i >> 2];
    return make_float4(bfbits(u.x), bfbits(u.y), bfbits(u.z), bfbits(u.w));
}

// ---------------- count (+ dtype detect in the extra block) ----------------
// detect: first 10112 uint32 of W1 (40448 B, safe in both layouts). bf16-packed:
// low half is |w|<1 -> exp<128. fp32: low 16 bits are mantissa noise -> exp>=128
// about half the time.

__global__ void k_count(const int* __restrict__ edst, int* __restrict__ deg,
                        const unsigned int* __restrict__ w1, int* __restrict__ flag) {
    int t = threadIdx.x;
    if (blockIdx.x == gridDim.x - 1) {
        __shared__ int sm[256];
        int c = 0;
        for (int i = t; i < 10112; i += 256) {
            unsigned int e = (w1[i] >> 7) & 0xFFu;
            c += (e >= 128u) ? 1 : 0;
        }
        sm[t] = c;
        __syncthreads();
        for (int off = 128; off > 0; off >>= 1) {
            if (t < off) sm[t] += sm[t + off];
            __syncthreads();
        }
        if (t == 0) flag[0] = (sm[0] > 500) ? 1 : 0;
        return;
    }
    int e = blockIdx.x * 256 + t;
    if (e < EE) atomicAdd(&deg[edst[e]], 1);
}

// ---------------- CSR scan ----------------

__global__ void k_scan_block(const int* __restrict__ deg, int* __restrict__ partial,
                             int* __restrict__ bsums) {
    __shared__ int sm[256];
    int t = threadIdx.x;
    int i = blockIdx.x * 256 + t;
    int v = (i < NN) ? deg[i] : 0;
    sm[t] = v;
    __syncthreads();
    for (int off = 1; off < 256; off <<= 1) {
        int u = (t >= off) ? sm[t - off] : 0;
        __syncthreads();
        sm[t] += u;
        __syncthreads();
    }
    if (i < NN) partial[i] = sm[t];
    if (t == 255) bsums[blockIdx.x] = sm[255];
}

// finalize, with inline reduction of bsums[0..b) (grid=196 <= 256 threads)
__global__ void k_finalize(const int* __restrict__ deg, const int* __restrict__ partial,
                           const int* __restrict__ bsums, int* __restrict__ offsets,
                           float* __restrict__ dinv) {
    __shared__ int sm[256];
    int b = blockIdx.x;
    int t = threadIdx.x;
    sm[t] = (t < b) ? bsums[t] : 0;
    __syncthreads();
    for (int off = 128; off > 0; off >>= 1) {
        if (t < off) sm[t] += sm[t + off];
        __syncthreads();
    }
    int base = sm[0];
    int i = b * 256 + t;
    if (i >= NN) return;
    int incl = partial[i] + base;
    offsets[i] = incl - deg[i];
    if (i == NN - 1) offsets[NN] = incl;
    dinv[i] = rsqrtf((float)(deg[i] + 1));   // +1 self-loop
}

__global__ void k_fill(const int* __restrict__ esrc, const int* __restrict__ edst,
                       const int* __restrict__ offsets, int* __restrict__ cursor,
                       int* __restrict__ eidx) {
    int e = blockIdx.x * blockDim.x + threadIdx.x;
    if (e < EE) {
        int d = edst[e];
        int pos = atomicAdd(&cursor[d], 1);
        eidx[offsets[d] + pos] = esrc[e];
    }
}

// ---------------- layer 1: h1 = relu(GCN(one_hot(x), W1, b1)) ----------------

__global__ __launch_bounds__(256) void k_layer1(
        const int* __restrict__ x, const int* __restrict__ offsets,
        const int* __restrict__ eidx, const float* __restrict__ dinv,
        const void* __restrict__ W1, const void* __restrict__ b1,
        const int* __restrict__ flag, float* __restrict__ h1) {
    bool f32 = (*flag != 0);
    int node = blockIdx.x * 4 + (threadIdx.x >> 6);
    int lane = threadIdx.x & 63;
    int ch = lane * 4;
    if (node >= NN) return;
    int beg = offsets[node], end = offsets[node + 1];
    float4 acc = make_float4(0.f, 0.f, 0.f, 0.f);
    for (int p = beg; p < end; ++p) {
        int s = eidx[p];
        float dv = dinv[s];
        float4 w = ldf4(W1, x[s] * HH + ch, f32);
        acc.x += dv * w.x; acc.y += dv * w.y; acc.z += dv * w.z; acc.w += dv * w.w;
    }
    float di = dinv[node];
    float d2 = di * di;
    float4 ws = ldf4(W1, x[node] * HH + ch, f32);
    float4 bb = ldf4(b1, ch, f32);
    float4 o;
    o.x = fmaxf(di * acc.x + d2 * ws.x + bb.x, 0.f);
    o.y = fmaxf(di * acc.y + d2 * ws.y + bb.y, 0.f);
    o.z = fmaxf(di * acc.z + d2 * ws.z + bb.z, 0.f);
    o.w = fmaxf(di * acc.w + d2 * ws.w + bb.w, 0.f);
    ((float4*)h1)[(node * HH + ch) >> 2] = o;
}

// ---------------- agg2 = A_norm @ h1 (wave-per-node, XCD-swizzled) ----------------
// Bijection: 12500 = 8*1562 + 4; first 12496 -> 8 contiguous per-XCD ranges, tail id.

__global__ __launch_bounds__(256) void k_agg2(
        const int* __restrict__ offsets, const int* __restrict__ eidx,
        const float* __restrict__ dinv, const float* __restrict__ h1,
        float* __restrict__ agg2) {
    int b = blockIdx.x;
    int grp = (b < 12496) ? ((b & 7) * 1562 + (b >> 3)) : b;
    int node = grp * 4 + (threadIdx.x >> 6);
    int lane = threadIdx.x & 63;
    int ch = lane * 4;
    if (node >= NN) return;
    int beg = offsets[node], end = offsets[node + 1];
    float4 acc = make_float4(0.f, 0.f, 0.f, 0.f);
    for (int p = beg; p < end; ++p) {
        int s = eidx[p];
        float dv = dinv[s];
        float4 v = ((const float4*)h1)[(s * HH + ch) >> 2];
        acc.x += dv * v.x; acc.y += dv * v.y; acc.z += dv * v.z; acc.w += dv * v.w;
    }
    float di = dinv[node];
    float d2 = di * di;
    float4 v = ((const float4*)h1)[(node * HH + ch) >> 2];
    float4 o;
    o.x = di * acc.x + d2 * v.x;
    o.y = di * acc.y + d2 * v.y;
    o.z = di * acc.z + d2 * v.z;
    o.w = di * acc.w + d2 * v.w;
    ((float4*)agg2)[(node * HH + ch) >> 2] = o;
}

// ---------------- h2 = relu(agg2 @ W2 + b2) + fused scorer dots ----------------
// r4-proven shape: 32 rows x 256 cols per block (grid 1563), A staged in LDS
// ONCE (one barrier pair for the whole kernel), W2 streamed per-k from global
// (coalesced, L1/L2-served) with an explicit one-group software prefetch.
// Per thread: 8 rows (rg = t>>6) x 4 cols (c4 = t&63). A reads from LDS are
// wave-uniform broadcasts -> bank-conflict-free -> NO pad (32 KB = 5 blocks/CU).

__global__ __launch_bounds__(256) void k_gemm2(
        const float* __restrict__ A, const void* __restrict__ W2,
        const void* __restrict__ b2, const void* __restrict__ Wrel,
        const void* __restrict__ Wroot, const int* __restrict__ flag,
        float* __restrict__ Y, float* __restrict__ trel, float* __restrict__ troot) {
    __shared__ float As[GR][HH];     // 32 KB, no pad (broadcast reads)
    bool f32 = (*flag != 0);
    int t = threadIdx.x;
    int c4 = t & 63;          // float4 column index: cols 4*c4 .. 4*c4+3
    int rg = t >> 6;          // wave id -> rows rg*8 .. rg*8+7
    int r0 = blockIdx.x * GR;

    // stage A tile (32 x 256) once: 2048 float4, 8 per thread
#pragma unroll
    for (int j = 0; j < 8; ++j) {
        int i = t + j * 256;
        int r = i >> 6;
        int c = (i & 63) * 4;
        int row = r0 + r;
        float4 v = (row < NN) ? *(const float4*)&A[row * HH + c]
                              : make_float4(0.f, 0.f, 0.f, 0.f);
        *(float4*)&As[r][c] = v;
    }
    __syncthreads();

    float4 acc[8];
#pragma unroll
    for (int rr = 0; rr < 8; ++rr) acc[rr] = make_float4(0.f, 0.f, 0.f, 0.f);

    if (f32) {
        const float* W = (const float*)W2;
        float4 w0 = *(const float4*)&W[0 * HH + c4 * 4];
        float4 w1 = *(const float4*)&W[1 * HH + c4 * 4];
        float4 w2 = *(const float4*)&W[2 * HH + c4 * 4];
        float4 w3 = *(const float4*)&W[3 * HH + c4 * 4];
        for (int k = 0; k < 256; k += 4) {
            float4 n0, n1, n2, n3;
            int kn = (k + 4) & 255;          // wraps to 0 on last iter (harmless)
            n0 = *(const float4*)&W[(kn + 0) * HH + c4 * 4];
            n1 = *(const float4*)&W[(kn + 1) * HH + c4 * 4];
            n2 = *(const float4*)&W[(kn + 2) * HH + c4 * 4];
            n3 = *(const float4*)&W[(kn + 3) * HH + c4 * 4];
#pragma unroll
            for (int rr = 0; rr < 8; ++rr) {
                float4 a = *(const float4*)&As[rg * 8 + rr][k];
                acc[rr].x += a.x * w0.x + a.y * w1.x + a.z * w2.x + a.w * w3.x;
                acc[rr].y += a.x * w0.y + a.y * w1.y + a.z * w2.y + a.w * w3.y;
                acc[rr].z += a.x * w0.z + a.y * w1.z + a.z * w2.z + a.w * w3.z;
                acc[rr].w += a.x * w0.w + a.y * w1.w + a.z * w2.w + a.w * w3.w;
            }
            w0 = n0; w1 = n1; w2 = n2; w3 = n3;
        }
    } else {
        const unsigned short* W = (const unsigned short*)W2;
        ushort4 u0 = *(const ushort4*)&W[0 * HH + c4 * 4];
        ushort4 u1 = *(const ushort4*)&W[1 * HH + c4 * 4];
        ushort4 u2 = *(const ushort4*)&W[2 * HH + c4 * 4];
        ushort4 u3 = *(const ushort4*)&W[3 * HH + c4 * 4];
        for (int k = 0; k < 256; k += 4) {
            ushort4 m0, m1, m2, m3;
            int kn = (k + 4) & 255;
            m0 = *(const ushort4*)&W[(kn + 0) * HH + c4 * 4];
            m1 = *(const ushort4*)&W[(kn + 1) * HH + c4 * 4];
            m2 = *(const ushort4*)&W[(kn + 2) * HH + c4 * 4];
            m3 = *(const ushort4*)&W[(kn + 3) * HH + c4 * 4];
            float4 w0 = make_float4(bfbits(u0.x), bfbits(u0.y), bfbits(u0.z), bfbits(u0.w));
            float4 w1 = make_float4(bfbits(u1.x), bfbits(u1.y), bfbits(u1.z), bfbits(u1.w));
            float4 w2 = make_float4(bfbits(u2.x), bfbits(u2.y), bfbits(u2.z), bfbits(u2.w));
            float4 w3 = make_float4(bfbits(u3.x), bfbits(u3.y), bfbits(u3.z), bfbits(u3.w));
#pragma unroll
            for (int rr = 0; rr < 8; ++rr) {
                float4 a = *(const float4*)&As[rg * 8 + rr][k];
                acc[rr].x += a.x * w0.x + a.y * w1.x + a.z * w2.x + a.w * w3.x;
                acc[rr].y += a.x * w0.y + a.y * w1.y + a.z * w2.y + a.w * w3.y;
                acc[rr].z += a.x * w0.z + a.y * w1.z + a.z * w2.z + a.w * w3.z;
                acc[rr].w += a.x * w0.w + a.y * w1.w + a.z * w2.w + a.w * w3.w;
            }
            u0 = m0; u1 = m1; u2 = m2; u3 = m3;
        }
    }

    float4 bb = ldf4(b2, c4 * 4, f32);
    float4 wr = ldf4(Wrel, c4 * 4, f32);
    float4 wo = ldf4(Wroot, c4 * 4, f32);
#pragma unroll
    for (int rr = 0; rr < 8; ++rr) {
        int row = r0 + rg * 8 + rr;
        float4 y;
        y.x = fmaxf(acc[rr].x + bb.x, 0.f);
        y.y = fmaxf(acc[rr].y + bb.y, 0.f);
        y.z = fmaxf(acc[rr].z + bb.z, 0.f);
        y.w = fmaxf(acc[rr].w + bb.w, 0.f);
        if (row < NN)
            *(float4*)&Y[row * HH + c4 * 4] = y;
        float sr = y.x * wr.x + y.y * wr.y + y.z * wr.z + y.w * wr.w;
        float so = y.x * wo.x + y.y * wo.y + y.z * wo.z + y.w * wo.w;
#pragma unroll
        for (int off = 32; off > 0; off >>= 1) {
            sr += __shfl_xor(sr, off, 64);
            so += __shfl_xor(so, off, 64);
        }
        if (c4 == 0 && row < NN) { trel[row] = sr; troot[row] = so; }
    }
}

// ---------------- fused: score -> per-graph top-k -> tanh-weighted max-pool ------
// One block per graph, 1024 threads (one bitonic element per thread).
// Desc score, asc index = jax.lax.top_k tie-break.

__global__ __launch_bounds__(1024) void k_topk(
        const int* __restrict__ offsets, const int* __restrict__ eidx,
        const float* __restrict__ trel, const float* __restrict__ troot,
        const void* __restrict__ brel, const int* __restrict__ flag,
        const float* __restrict__ h2, void* __restrict__ out) {
    __shared__ float s[1024];
    __shared__ int   id[1024];
    __shared__ float sw[KK];
    __shared__ int   snode[KK];
    bool f32 = (*flag != 0);
    int b = blockIdx.x, t = threadIdx.x;
    float br = ldf(brel, 0, f32);
    if (t < NPGc) {
        int node = b * NPGc + t;
        float sc = br + troot[node];
        int beg = offsets[node], end = offsets[node + 1];
        for (int p = beg; p < end; ++p) sc += trel[eidx[p]];
        s[t] = sc; id[t] = t;
    } else { s[t] = -FLT_MAX; id[t] = 0x7FFFFFFF; }
    for (int k = 2; k <= 1024; k <<= 1) {
        for (int j = k >> 1; j > 0; j >>= 1) {
            __syncthreads();
            int l = t ^ j;
            if (l > t) {
                float si = s[t], sl = s[l];
                int   ii = id[t], il = id[l];
                bool iFirst = (si > sl) || (si == sl && ii < il);
                bool doSwap = ((t & k) == 0) ? (!iFirst) : iFirst;
                if (doSwap) { s[t] = sl; s[l] = si; id[t] = il; id[l] = ii; }
            }
        }
    }
    __syncthreads();
    if (t < KK) {
        snode[t] = b * NPGc + id[t];
        sw[t]    = tanhf(s[t]);
    }
    __syncthreads();
    // pool: col = t&255, quarter = t>>8 handles 125 selected rows
    int col = t & 255;
    int q4 = t >> 8;
    float m = -FLT_MAX;
    for (int q = q4 * 125; q < q4 * 125 + 125; ++q) {
        float v = h2[snode[q] * HH + col] * sw[q];
        m = fmaxf(m, v);
    }
    __syncthreads();          // s[] reuse
    s[q4 * 256 + col] = m;
    __syncthreads();
    if (t < 256) {
        float r = fmaxf(fmaxf(s[t], s[256 + t]), fmaxf(s[512 + t], s[768 + t]));
        if (f32) ((float*)out)[b * HH + t] = r;
        else     ((bf16*)out)[b * HH + t] = __float2bfloat16(r);
    }
}

// ---------------- launch ----------------

extern "C" void kernel_launch(void* const* d_in, const int* in_sizes, int n_in,
                              void* d_out, int out_size, void* d_ws, size_t ws_size,
                              hipStream_t stream) {
    const int*  x    = (const int*)d_in[0];
    const int*  esrc = (const int*)d_in[1];
    const int*  edst = esrc + EE;
    const void* W1   = d_in[3];
    const void* b1   = d_in[4];
    const void* W2   = d_in[5];
    const void* b2   = d_in[6];
    const void* Wrel = d_in[7];
    const void* brel = d_in[8];
    const void* Wroot= d_in[9];

    char* w = (char*)d_ws;
    size_t off = 0;
    auto carve = [&](size_t bytes) -> void* {
        void* p = w + off;
        off = (off + bytes + 255) & ~(size_t)255;
        return p;
    };
    int*   flag    = (int*)  carve(256);
    int*   deg     = (int*)  carve((size_t)2 * NN * 4); // deg + cursor in ONE
    int*   cursor  = deg + NN;                          // carve: memset covers both
    int*   partial = (int*)  carve((size_t)NN * 4);
    int*   bsums   = (int*)  carve(256 * 4);
    int*   offsets = (int*)  carve((size_t)(NN + 1) * 4);
    int*   eidx    = (int*)  carve((size_t)EE * 4);
    float* dinv    = (float*)carve((size_t)NN * 4);
    float* trel    = (float*)carve((size_t)NN * 4);
    float* troot   = (float*)carve((size_t)NN * 4);
    float* bufA    = (float*)carve((size_t)NN * HH * 4);  // h1, then h2
    float* bufB    = (float*)carve((size_t)NN * HH * 4);  // agg2
    (void)ws_size; (void)in_sizes; (void)n_in; (void)out_size;

    const int NB   = (NN + 255) / 256;     // 196
    const int EBLK = (EE + 255) / 256;     // 1172
    const int NGB  = (NN + 3) / 4;         // 12500

    hipMemsetAsync(deg, 0, (size_t)2 * NN * 4, stream);  // deg + cursor exactly
    k_count     <<<EBLK + 1, 256, 0, stream>>>(edst, deg, (const unsigned int*)W1, flag);
    k_scan_block<<<NB, 256, 0, stream>>>(deg, partial, bsums);
    k_finalize  <<<NB, 256, 0, stream>>>(deg, partial, bsums, offsets, dinv);
    k_fill      <<<EBLK, 256, 0, stream>>>(esrc, edst, offsets, cursor, eidx);

    k_layer1    <<<NGB, 256, 0, stream>>>(x, offsets, eidx, dinv, W1, b1, flag, bufA);
    k_agg2      <<<NGB, 256, 0, stream>>>(offsets, eidx, dinv, bufA, bufB);
    k_gemm2     <<<(NN + GR - 1) / GR, 256, 0, stream>>>(bufB, W2, b2, Wrel, Wroot,
                                                         flag, bufA, trel, troot);
    k_topk      <<<BB, 1024, 0, stream>>>(offsets, eidx, trel, troot, brel, flag,
                                          bufA, d_out);
}

// Round 10
// 309.767 us; speedup vs baseline: 1.5692x; 1.0890x over previous
//
#include <hip/hip_runtime.h>
#include <hip/hip_bf16.h>
#include <float.h>
#include <math.h>

#define NN   50000
#define BB   50
#define NPGc 1000
#define EE   300000
#define HH   256
#define FIN  79
#define KK   500
#define GR   32      // gemm rows per block

typedef __hip_bfloat16 bf16;
typedef float v2f __attribute__((ext_vector_type(2)));

__device__ __forceinline__ float bfbits(unsigned short h) {
    return __uint_as_float(((unsigned int)h) << 16);
}
__device__ __forceinline__ float ldf(const void* p, int i, bool f32) {
    return f32 ? ((const float*)p)[i] : bfbits(((const unsigned short*)p)[i]);
}
__device__ __forceinline__ float4 ldf4(const void* p, int i, bool f32) {
    if (f32) return ((const float4*)p)[i >> 2];
    ushort4 u = ((const ushort4*)p)[i >> 2];
    return make_float4(bfbits(u.x), bfbits(u.y), bfbits(u.z), bfbits(u.w));
}

// ---------------- count (+ dtype detect in the extra block) ----------------
// detect: first 10112 uint32 of W1 (40448 B, safe in both layouts). bf16-packed:
// low half is |w|<1 -> exp<128. fp32: low 16 bits are mantissa noise -> exp>=128
// about half the time.

__global__ void k_count(const int* __restrict__ edst, int* __restrict__ deg,
                        const unsigned int* __restrict__ w1, int* __restrict__ flag) {
    int t = threadIdx.x;
    if (blockIdx.x == gridDim.x - 1) {
        __shared__ int sm[256];
        int c = 0;
        for (int i = t; i < 10112; i += 256) {
            unsigned int e = (w1[i] >> 7) & 0xFFu;
            c += (e >= 128u) ? 1 : 0;
        }
        sm[t] = c;
        __syncthreads();
        for (int off = 128; off > 0; off >>= 1) {
            if (t < off) sm[t] += sm[t + off];
            __syncthreads();
        }
        if (t == 0) flag[0] = (sm[0] > 500) ? 1 : 0;
        return;
    }
    int e = blockIdx.x * 256 + t;
    if (e < EE) atomicAdd(&deg[edst[e]], 1);
}

// ---------------- CSR scan ----------------

__global__ void k_scan_block(const int* __restrict__ deg, int* __restrict__ partial,
                             int* __restrict__ bsums) {
    __shared__ int sm[256];
    int t = threadIdx.x;
    int i = blockIdx.x * 256 + t;
    int v = (i < NN) ? deg[i] : 0;
    sm[t] = v;
    __syncthreads();
    for (int off = 1; off < 256; off <<= 1) {
        int u = (t >= off) ? sm[t - off] : 0;
        __syncthreads();
        sm[t] += u;
        __syncthreads();
    }
    if (i < NN) partial[i] = sm[t];
    if (t == 255) bsums[blockIdx.x] = sm[255];
}

// finalize, with inline reduction of bsums[0..b) (grid=196 <= 256 threads)
__global__ void k_finalize(const int* __restrict__ deg, const int* __restrict__ partial,
                           const int* __restrict__ bsums, int* __restrict__ offsets,
                           float* __restrict__ dinv) {
    __shared__ int sm[256];
    int b = blockIdx.x;
    int t = threadIdx.x;
    sm[t] = (t < b) ? bsums[t] : 0;
    __syncthreads();
    for (int off = 128; off > 0; off >>= 1) {
        if (t < off) sm[t] += sm[t + off];
        __syncthreads();
    }
    int base = sm[0];
    int i = b * 256 + t;
    if (i >= NN) return;
    int incl = partial[i] + base;
    offsets[i] = incl - deg[i];
    if (i == NN - 1) offsets[NN] = incl;
    dinv[i] = rsqrtf((float)(deg[i] + 1));   // +1 self-loop
}

__global__ void k_fill(const int* __restrict__ esrc, const int* __restrict__ edst,
                       const int* __restrict__ offsets, int* __restrict__ cursor,
                       int* __restrict__ eidx) {
    int e = blockIdx.x * blockDim.x + threadIdx.x;
    if (e < EE) {
        int d = edst[e];
        int pos = atomicAdd(&cursor[d], 1);
        eidx[offsets[d] + pos] = esrc[e];
    }
}

// ---------------- layer 1: h1 = relu(GCN(one_hot(x), W1, b1)) ----------------
// Wave-per-node; lane-parallel prefetch of eidx/x/dinv, shfl-broadcast per edge
// so the row gathers issue back-to-back (no serial eidx->row chains).

__global__ __launch_bounds__(256) void k_layer1(
        const int* __restrict__ x, const int* __restrict__ offsets,
        const int* __restrict__ eidx, const float* __restrict__ dinv,
        const void* __restrict__ W1, const void* __restrict__ b1,
        const int* __restrict__ flag, float* __restrict__ h1) {
    bool f32 = (*flag != 0);
    int node = blockIdx.x * 4 + (threadIdx.x >> 6);
    int lane = threadIdx.x & 63;
    int ch = lane * 4;
    if (node >= NN) return;
    int beg = offsets[node], end = offsets[node + 1];
    float4 acc = make_float4(0.f, 0.f, 0.f, 0.f);
    for (int base = beg; base < end; base += 64) {
        int cnt = min(64, end - base);
        int p  = base + ((lane < cnt) ? lane : 0);
        int sl = eidx[p];
        int xl = x[sl];
        float dvl = dinv[sl];
        for (int q = 0; q < cnt; ++q) {
            int xs   = __shfl(xl, q, 64);
            float dv = __shfl(dvl, q, 64);
            float4 w = ldf4(W1, xs * HH + ch, f32);
            acc.x += dv * w.x; acc.y += dv * w.y; acc.z += dv * w.z; acc.w += dv * w.w;
        }
    }
    float di = dinv[node];
    float d2 = di * di;
    float4 ws = ldf4(W1, x[node] * HH + ch, f32);
    float4 bb = ldf4(b1, ch, f32);
    float4 o;
    o.x = fmaxf(di * acc.x + d2 * ws.x + bb.x, 0.f);
    o.y = fmaxf(di * acc.y + d2 * ws.y + bb.y, 0.f);
    o.z = fmaxf(di * acc.z + d2 * ws.z + bb.z, 0.f);
    o.w = fmaxf(di * acc.w + d2 * ws.w + bb.w, 0.f);
    ((float4*)h1)[(node * HH + ch) >> 2] = o;
}

// ---------------- agg2 = A_norm @ h1 (wave-per-node, XCD-swizzled) ----------------
// Bijection: 12500 = 8*1562 + 4; first 12496 -> 8 contiguous per-XCD ranges, tail id.
// Same shfl-broadcast edge prefetch as k_layer1.

__global__ __launch_bounds__(256) void k_agg2(
        const int* __restrict__ offsets, const int* __restrict__ eidx,
        const float* __restrict__ dinv, const float* __restrict__ h1,
        float* __restrict__ agg2) {
    int b = blockIdx.x;
    int grp = (b < 12496) ? ((b & 7) * 1562 + (b >> 3)) : b;
    int node = grp * 4 + (threadIdx.x >> 6);
    int lane = threadIdx.x & 63;
    int ch = lane * 4;
    if (node >= NN) return;
    int beg = offsets[node], end = offsets[node + 1];
    float4 acc = make_float4(0.f, 0.f, 0.f, 0.f);
    for (int base = beg; base < end; base += 64) {
        int cnt = min(64, end - base);
        int p  = base + ((lane < cnt) ? lane : 0);
        int sl = eidx[p];
        float dvl = dinv[sl];
        for (int q = 0; q < cnt; ++q) {
            int s    = __shfl(sl, q, 64);
            float dv = __shfl(dvl, q, 64);
            float4 v = ((const float4*)h1)[(s * HH + ch) >> 2];
            acc.x += dv * v.x; acc.y += dv * v.y; acc.z += dv * v.z; acc.w += dv * v.w;
        }
    }
    float di = dinv[node];
    float d2 = di * di;
    float4 v = ((const float4*)h1)[(node * HH + ch) >> 2];
    float4 o;
    o.x = di * acc.x + d2 * v.x;
    o.y = di * acc.y + d2 * v.y;
    o.z = di * acc.z + d2 * v.z;
    o.w = di * acc.w + d2 * v.w;
    ((float4*)agg2)[(node * HH + ch) >> 2] = o;
}

// ---------------- h2 = relu(agg2 @ W2 + b2) + fused scorer dots ----------------
// r4/r9 shape: 32 rows x 256 cols per block (grid 1563), A staged in LDS once,
// W2 streamed per-k from global with one-group software prefetch. Accumulation
// done in float2 ext-vectors so the backend can emit v_pk_fma_f32 (2 fp32
// FMA/instr -> halves FMA issue cycles; scalarizes harmlessly if unsupported).

__global__ __launch_bounds__(256) void k_gemm2(
        const float* __restrict__ A, const void* __restrict__ W2,
        const void* __restrict__ b2, const void* __restrict__ Wrel,
        const void* __restrict__ Wroot, const int* __restrict__ flag,
        float* __restrict__ Y, float* __restrict__ trel, float* __restrict__ troot) {
    __shared__ float As[GR][HH];     // 32 KB, no pad (broadcast reads)
    bool f32 = (*flag != 0);
    int t = threadIdx.x;
    int c4 = t & 63;          // float4 column index: cols 4*c4 .. 4*c4+3
    int rg = t >> 6;          // wave id -> rows rg*8 .. rg*8+7
    int r0 = blockIdx.x * GR;

    // stage A tile (32 x 256) once: 2048 float4, 8 per thread
#pragma unroll
    for (int j = 0; j < 8; ++j) {
        int i = t + j * 256;
        int r = i >> 6;
        int c = (i & 63) * 4;
        int row = r0 + r;
        float4 v = (row < NN) ? *(const float4*)&A[row * HH + c]
                              : make_float4(0.f, 0.f, 0.f, 0.f);
        *(float4*)&As[r][c] = v;
    }
    __syncthreads();

    v2f accL[8], accH[8];
#pragma unroll
    for (int rr = 0; rr < 8; ++rr) { accL[rr] = (v2f)0.f; accH[rr] = (v2f)0.f; }

    if (f32) {
        const float* W = (const float*)W2;
        float4 w0 = *(const float4*)&W[0 * HH + c4 * 4];
        float4 w1 = *(const float4*)&W[1 * HH + c4 * 4];
        float4 w2 = *(const float4*)&W[2 * HH + c4 * 4];
        float4 w3 = *(const float4*)&W[3 * HH + c4 * 4];
        for (int k = 0; k < 256; k += 4) {
            float4 n0, n1, n2, n3;
            int kn = (k + 4) & 255;          // wraps to 0 on last iter (harmless)
            n0 = *(const float4*)&W[(kn + 0) * HH + c4 * 4];
            n1 = *(const float4*)&W[(kn + 1) * HH + c4 * 4];
            n2 = *(const float4*)&W[(kn + 2) * HH + c4 * 4];
            n3 = *(const float4*)&W[(kn + 3) * HH + c4 * 4];
            v2f w0L = {w0.x, w0.y}, w0H = {w0.z, w0.w};
            v2f w1L = {w1.x, w1.y}, w1H = {w1.z, w1.w};
            v2f w2L = {w2.x, w2.y}, w2H = {w2.z, w2.w};
            v2f w3L = {w3.x, w3.y}, w3H = {w3.z, w3.w};
#pragma unroll
            for (int rr = 0; rr < 8; ++rr) {
                float4 a = *(const float4*)&As[rg * 8 + rr][k];
                v2f ax = a.x, ay = a.y, az = a.z, aw = a.w;
                accL[rr] += ax * w0L; accH[rr] += ax * w0H;
                accL[rr] += ay * w1L; accH[rr] += ay * w1H;
                accL[rr] += az * w2L; accH[rr] += az * w2H;
                accL[rr] += aw * w3L; accH[rr] += aw * w3H;
            }
            w0 = n0; w1 = n1; w2 = n2; w3 = n3;
        }
    } else {
        const unsigned short* W = (const unsigned short*)W2;
        ushort4 u0 = *(const ushort4*)&W[0 * HH + c4 * 4];
        ushort4 u1 = *(const ushort4*)&W[1 * HH + c4 * 4];
        ushort4 u2 = *(const ushort4*)&W[2 * HH + c4 * 4];
        ushort4 u3 = *(const ushort4*)&W[3 * HH + c4 * 4];
        for (int k = 0; k < 256; k += 4) {
            ushort4 m0, m1, m2, m3;
            int kn = (k + 4) & 255;
            m0 = *(const ushort4*)&W[(kn + 0) * HH + c4 * 4];
            m1 = *(const ushort4*)&W[(kn + 1) * HH + c4 * 4];
            m2 = *(const ushort4*)&W[(kn + 2) * HH + c4 * 4];
            m3 = *(const ushort4*)&W[(kn + 3) * HH + c4 * 4];
            v2f w0L = {bfbits(u0.x), bfbits(u0.y)}, w0H = {bfbits(u0.z), bfbits(u0.w)};
            v2f w1L = {bfbits(u1.x), bfbits(u1.y)}, w1H = {bfbits(u1.z), bfbits(u1.w)};
            v2f w2L = {bfbits(u2.x), bfbits(u2.y)}, w2H = {bfbits(u2.z), bfbits(u2.w)};
            v2f w3L = {bfbits(u3.x), bfbits(u3.y)}, w3H = {bfbits(u3.z), bfbits(u3.w)};
#pragma unroll
            for (int rr = 0; rr < 8; ++rr) {
                float4 a = *(const float4*)&As[rg * 8 + rr][k];
                v2f ax = a.x, ay = a.y, az = a.z, aw = a.w;
                accL[rr] += ax * w0L; accH[rr] += ax * w0H;
                accL[rr] += ay * w1L; accH[rr] += ay * w1H;
                accL[rr] += az * w2L; accH[rr] += az * w2H;
                accL[rr] += aw * w3L; accH[rr] += aw * w3H;
            }
            u0 = m0; u1 = m1; u2 = m2; u3 = m3;
        }
    }

    float4 bb = ldf4(b2, c4 * 4, f32);
    float4 wr = ldf4(Wrel, c4 * 4, f32);
    float4 wo = ldf4(Wroot, c4 * 4, f32);
#pragma unroll
    for (int rr = 0; rr < 8; ++rr) {
        int row = r0 + rg * 8 + rr;
        float4 y;
        y.x = fmaxf(accL[rr].x + bb.x, 0.f);
        y.y = fmaxf(accL[rr].y + bb.y, 0.f);
        y.z = fmaxf(accH[rr].x + bb.z, 0.f);
        y.w = fmaxf(accH[rr].y + bb.w, 0.f);
        if (row < NN)
            *(float4*)&Y[row * HH + c4 * 4] = y;
        float sr = y.x * wr.x + y.y * wr.y + y.z * wr.z + y.w * wr.w;
        float so = y.x * wo.x + y.y * wo.y + y.z * wo.z + y.w * wo.w;
#pragma unroll
        for (int off = 32; off > 0; off >>= 1) {
            sr += __shfl_xor(sr, off, 64);
            so += __shfl_xor(so, off, 64);
        }
        if (c4 == 0 && row < NN) { trel[row] = sr; troot[row] = so; }
    }
}

// ---------------- fused: score -> per-graph top-k -> tanh-weighted max-pool ------
// One block per graph, 1024 threads (one bitonic element per thread).
// Desc score, asc index = jax.lax.top_k tie-break.

__global__ __launch_bounds__(1024) void k_topk(
        const int* __restrict__ offsets, const int* __restrict__ eidx,
        const float* __restrict__ trel, const float* __restrict__ troot,
        const void* __restrict__ brel, const int* __restrict__ flag,
        const float* __restrict__ h2, void* __restrict__ out) {
    __shared__ float s[1024];
    __shared__ int   id[1024];
    __shared__ float sw[KK];
    __shared__ int   snode[KK];
    bool f32 = (*flag != 0);
    int b = blockIdx.x, t = threadIdx.x;
    float br = ldf(brel, 0, f32);
    if (t < NPGc) {
        int node = b * NPGc + t;
        float sc = br + troot[node];
        int beg = offsets[node], end = offsets[node + 1];
        for (int p = beg; p < end; ++p) sc += trel[eidx[p]];
        s[t] = sc; id[t] = t;
    } else { s[t] = -FLT_MAX; id[t] = 0x7FFFFFFF; }
    for (int k = 2; k <= 1024; k <<= 1) {
        for (int j = k >> 1; j > 0; j >>= 1) {
            __syncthreads();
            int l = t ^ j;
            if (l > t) {
                float si = s[t], sl = s[l];
                int   ii = id[t], il = id[l];
                bool iFirst = (si > sl) || (si == sl && ii < il);
                bool doSwap = ((t & k) == 0) ? (!iFirst) : iFirst;
                if (doSwap) { s[t] = sl; s[l] = si; id[t] = il; id[l] = ii; }
            }
        }
    }
    __syncthreads();
    if (t < KK) {
        snode[t] = b * NPGc + id[t];
        sw[t]    = tanhf(s[t]);
    }
    __syncthreads();
    // pool: col = t&255, quarter = t>>8 handles 125 selected rows
    int col = t & 255;
    int q4 = t >> 8;
    float m = -FLT_MAX;
    for (int q = q4 * 125; q < q4 * 125 + 125; ++q) {
        float v = h2[snode[q] * HH + col] * sw[q];
        m = fmaxf(m, v);
    }
    __syncthreads();          // s[] reuse
    s[q4 * 256 + col] = m;
    __syncthreads();
    if (t < 256) {
        float r = fmaxf(fmaxf(s[t], s[256 + t]), fmaxf(s[512 + t], s[768 + t]));
        if (f32) ((float*)out)[b * HH + t] = r;
        else     ((bf16*)out)[b * HH + t] = __float2bfloat16(r);
    }
}

// ---------------- launch ----------------

extern "C" void kernel_launch(void* const* d_in, const int* in_sizes, int n_in,
                              void* d_out, int out_size, void* d_ws, size_t ws_size,
                              hipStream_t stream) {
    const int*  x    = (const int*)d_in[0];
    const int*  esrc = (const int*)d_in[1];
    const int*  edst = esrc + EE;
    const void* W1   = d_in[3];
    const void* b1   = d_in[4];
    const void* W2   = d_in[5];
    const void* b2   = d_in[6];
    const void* Wrel = d_in[7];
    const void* brel = d_in[8];
    const void* Wroot= d_in[9];

    char* w = (char*)d_ws;
    size_t off = 0;
    auto carve = [&](size_t bytes) -> void* {
        void* p = w + off;
        off = (off + bytes + 255) & ~(size_t)255;
        return p;
    };
    int*   flag    = (int*)  carve(256);
    int*   deg     = (int*)  carve((size_t)2 * NN * 4); // deg + cursor in ONE
    int*   cursor  = deg + NN;                          // carve: memset covers both
    int*   partial = (int*)  carve((size_t)NN * 4);
    int*   bsums   = (int*)  carve(256 * 4);
    int*   offsets = (int*)  carve((size_t)(NN + 1) * 4);
    int*   eidx    = (int*)  carve((size_t)EE * 4);
    float* dinv    = (float*)carve((size_t)NN * 4);
    float* trel    = (float*)carve((size_t)NN * 4);
    float* troot   = (float*)carve((size_t)NN * 4);
    float* bufA    = (float*)carve((size_t)NN * HH * 4);  // h1, then h2
    float* bufB    = (float*)carve((size_t)NN * HH * 4);  // agg2
    (void)ws_size; (void)in_sizes; (void)n_in; (void)out_size;

    const int NB   = (NN + 255) / 256;     // 196
    const int EBLK = (EE + 255) / 256;     // 1172
    const int NGB  = (NN + 3) / 4;         // 12500

    hipMemsetAsync(deg, 0, (size_t)2 * NN * 4, stream);  // deg + cursor exactly
    k_count     <<<EBLK + 1, 256, 0, stream>>>(edst, deg, (const unsigned int*)W1, flag);
    k_scan_block<<<NB, 256, 0, stream>>>(deg, partial, bsums);
    k_finalize  <<<NB, 256, 0, stream>>>(deg, partial, bsums, offsets, dinv);
    k_fill      <<<EBLK, 256, 0, stream>>>(esrc, edst, offsets, cursor, eidx);

    k_layer1    <<<NGB, 256, 0, stream>>>(x, offsets, eidx, dinv, W1, b1, flag, bufA);
    k_agg2      <<<NGB, 256, 0, stream>>>(offsets, eidx, dinv, bufA, bufB);
    k_gemm2     <<<(NN + GR - 1) / GR, 256, 0, stream>>>(bufB, W2, b2, Wrel, Wroot,
                                                         flag, bufA, trel, troot);
    k_topk      <<<BB, 1024, 0, stream>>>(offsets, eidx, trel, troot, brel, flag,
                                          bufA, d_out);
}